// Round 1
// baseline (431.473 us; speedup 1.0000x reference)
//
#include <hip/hip_runtime.h>

typedef short short8 __attribute__((ext_vector_type(8)));
typedef float f32x4 __attribute__((ext_vector_type(4)));

#define N_NODES 100000
#define N_A     50000
#define N_EDGES 500000
#define N_T     4
#define D_IN    128
#define HF      128
#define BCOLS   144                  // 128 ft cols + 4 el + 4 er + 8 zero pad
#define TN      (N_T * N_NODES)
#define TE      (N_T * N_EDGES)
#define NB1     ((TN + 1023) / 1024) // 391 scan blocks

__device__ __forceinline__ unsigned short f2b(float f) {
  unsigned int u = __float_as_uint(f);
  u += 0x7FFFu + ((u >> 16) & 1u);
  return (unsigned short)(u >> 16);
}

// K0: build Bt[t][144][128] bf16 (column-major B so GEMM B-frags are contiguous):
// rows 0..127 = W[t][:,j], rows 128+h = W @ attn_l[h], rows 132+h = W @ attn_r[h], 136.. = 0
__global__ __launch_bounds__(256) void k_prepB(const float* __restrict__ W,
    const float* __restrict__ al, const float* __restrict__ ar,
    unsigned short* __restrict__ Bt)
{
  int idx = blockIdx.x * 256 + threadIdx.x;
  if (idx >= N_T * D_IN) return;
  int t = idx >> 7, k = idx & 127;
  const float* Wr = W + ((size_t)t * D_IN + k) * HF;
  unsigned short* o = Bt + (size_t)t * BCOLS * D_IN;
  for (int j = 0; j < HF; ++j) o[j * D_IN + k] = f2b(Wr[j]);
  for (int h = 0; h < 4; ++h) {
    float sl = 0.f, sr = 0.f;
    const float* alh = al + (t * 4 + h) * 32;
    const float* arh = ar + (t * 4 + h) * 32;
    for (int f = 0; f < 32; ++f) { float w = Wr[h * 32 + f]; sl += w * alh[f]; sr += w * arh[f]; }
    o[(128 + h) * D_IN + k] = f2b(sl);
    o[(132 + h) * D_IN + k] = f2b(sr);
  }
  for (int j = 136; j < 144; ++j) o[j * D_IN + k] = 0;
}

// K1: per-type projection GEMM. Block = 64 rows x 144 cols, 4 waves (16 rows each).
// Writes ft (bf16) + el/er (f32) pulled from the extra col-tile.
__global__ __launch_bounds__(256) void k_proj(const float* __restrict__ feat,
    const unsigned short* __restrict__ Btg,
    unsigned short* __restrict__ ftg,
    float* __restrict__ elg, float* __restrict__ erg)
{
  __shared__ __align__(16) unsigned short As[64 * 136];   // +8 pad: 2-way bank alias only
  __shared__ __align__(16) unsigned short Bs[144 * 136];
  const int t = blockIdx.y;
  const int row0 = blockIdx.x * 64;
  const int tid = threadIdx.x;

  for (int i = tid; i < 64 * 32; i += 256) {               // stage A: f32 -> bf16
    int r = i >> 5, c4 = (i & 31) << 2;
    int row = row0 + r;
    float4 v = make_float4(0.f, 0.f, 0.f, 0.f);
    if (row < N_NODES) v = *(const float4*)(feat + (size_t)row * D_IN + c4);
    unsigned int u01 = (unsigned int)f2b(v.x) | ((unsigned int)f2b(v.y) << 16);
    unsigned int u23 = (unsigned int)f2b(v.z) | ((unsigned int)f2b(v.w) << 16);
    *(uint2*)&As[r * 136 + c4] = make_uint2(u01, u23);
  }
  const uint4* bsrc = (const uint4*)(Btg + (size_t)t * BCOLS * D_IN);
  for (int i = tid; i < 144 * 16; i += 256) {              // stage Bt (already bf16)
    int r = i >> 4, c = i & 15;
    *(uint4*)&Bs[r * 136 + c * 8] = bsrc[r * 16 + c];
  }
  __syncthreads();

  const int wave = tid >> 6, lane = tid & 63;
  const int l15 = lane & 15, lk = (lane >> 4) * 8;
  const int wrow = wave * 16;
  short8 a[4];
#pragma unroll
  for (int kt = 0; kt < 4; ++kt)
    a[kt] = *(const short8*)&As[(wrow + l15) * 136 + kt * 32 + lk];
  f32x4 acc[9];
#pragma unroll
  for (int ct = 0; ct < 9; ++ct) {
    f32x4 c = {0.f, 0.f, 0.f, 0.f};
#pragma unroll
    for (int kt = 0; kt < 4; ++kt) {
      short8 b = *(const short8*)&Bs[(ct * 16 + l15) * 136 + kt * 32 + lk];
      c = __builtin_amdgcn_mfma_f32_16x16x32_bf16(a[kt], b, c, 0, 0, 0);
    }
    acc[ct] = c;
  }
  __syncthreads();                                         // all Bs reads done

  if (l15 < 8) {                                           // el/er from col-tile 8
#pragma unroll
    for (int r = 0; r < 4; ++r) {
      int row = row0 + wrow + (lane >> 4) * 4 + r;
      if (row < N_NODES) {
        float v = acc[8][r];
        if (l15 < 4) elg[((size_t)t * N_NODES + row) * 4 + l15] = v;
        else         erg[((size_t)t * N_NODES + row) * 4 + (l15 - 4)] = v;
      }
    }
  }
#pragma unroll
  for (int ct = 0; ct < 8; ++ct) {                         // stage C into Bs (reuse)
#pragma unroll
    for (int r = 0; r < 4; ++r) {
      int rr = wrow + (lane >> 4) * 4 + r;
      Bs[rr * 136 + ct * 16 + l15] = f2b(acc[ct][r]);
    }
  }
  __syncthreads();
  for (int i = tid; i < 64 * 16; i += 256) {               // coalesced ft write-out
    int r = i >> 4, c = i & 15;
    int row = row0 + r;
    if (row < N_NODES)
      *(uint4*)(ftg + ((size_t)t * N_NODES + row) * HF + c * 8) = *(const uint4*)&Bs[r * 136 + c * 8];
  }
}

// K2: counting sort of kept edges by (t,dst)
__global__ __launch_bounds__(256) void k_hist(const int* __restrict__ dst, int* __restrict__ cnt) {
  int idx = blockIdx.x * 256 + threadIdx.x;
  if (idx >= TE) return;
  int t = idx / N_EDGES;
  int d = dst[idx];
  bool keep = (t < 2) ? (d < N_A) : (d >= N_A);
  if (keep) atomicAdd(&cnt[t * N_NODES + d], 1);
}

__global__ __launch_bounds__(256) void k_scan1(const int* __restrict__ cnt,
    int* __restrict__ ofs, int* __restrict__ bsum) {
  __shared__ int ts[256];
  int b = blockIdx.x, t = threadIdx.x;
  int base = b * 1024 + t * 4;
  int v0 = 0, v1 = 0, v2 = 0, v3 = 0;
  if (base + 0 < TN) v0 = cnt[base + 0];
  if (base + 1 < TN) v1 = cnt[base + 1];
  if (base + 2 < TN) v2 = cnt[base + 2];
  if (base + 3 < TN) v3 = cnt[base + 3];
  int s = v0 + v1 + v2 + v3;
  ts[t] = s;
  __syncthreads();
  for (int o = 1; o < 256; o <<= 1) {
    int x = (t >= o) ? ts[t - o] : 0;
    __syncthreads();
    ts[t] += x;
    __syncthreads();
  }
  int run = ts[t] - s;
  if (base + 0 < TN) ofs[base + 0] = run; run += v0;
  if (base + 1 < TN) ofs[base + 1] = run; run += v1;
  if (base + 2 < TN) ofs[base + 2] = run; run += v2;
  if (base + 3 < TN) ofs[base + 3] = run;
  if (t == 255) bsum[b] = ts[255];
}

__global__ __launch_bounds__(512) void k_scan2(int* __restrict__ bsum) {
  __shared__ int ts[512];
  int t = threadIdx.x;
  int v = (t < NB1) ? bsum[t] : 0;
  ts[t] = v;
  __syncthreads();
  for (int o = 1; o < 512; o <<= 1) {
    int x = (t >= o) ? ts[t - o] : 0;
    __syncthreads();
    ts[t] += x;
    __syncthreads();
  }
  if (t < NB1) bsum[t] = ts[t] - v;
}

__global__ __launch_bounds__(256) void k_scan3(int* __restrict__ ofs, const int* __restrict__ bsum) {
  int b = blockIdx.x;
  int add = bsum[b];
  int base = b * 1024;
  for (int i = threadIdx.x; i < 1024; i += 256) {
    int j = base + i;
    if (j < TN) ofs[j] += add;
  }
}

__global__ __launch_bounds__(256) void k_scatter(const int* __restrict__ src, const int* __restrict__ dst,
    const int* __restrict__ ofs, int* __restrict__ cur, int* __restrict__ bucket) {
  int idx = blockIdx.x * 256 + threadIdx.x;
  if (idx >= TE) return;
  int t = idx / N_EDGES;
  int d = dst[idx];
  bool keep = (t < 2) ? (d < N_A) : (d >= N_A);
  if (!keep) return;
  int p = ofs[t * N_NODES + d] + atomicAdd(&cur[t * N_NODES + d], 1);
  bucket[p] = src[idx];
}

// K3: one wave per (node, slot): gather in-edges, unnormalized softmax-weighted sum, divide at end.
__global__ __launch_bounds__(256) void k_gather(const int* __restrict__ bucket,
    const int* __restrict__ ofs, const int* __restrict__ cnt,
    const unsigned int* __restrict__ ftu,
    const float* __restrict__ elg, const float* __restrict__ erg,
    float* __restrict__ agg)
{
  int wid = blockIdx.x * 4 + (threadIdx.x >> 6);
  int lane = threadIdx.x & 63;
  int n = wid >> 1, slot = wid & 1;
  if (n >= N_NODES) return;
  int t = slot + ((n >= N_A) ? 2 : 0);
  int h = lane >> 4;
  float erh = erg[((size_t)t * N_NODES + n) * 4 + h];
  int base = ofs[t * N_NODES + n];
  int c = cnt[t * N_NODES + n];
  float ax = 0.f, ay = 0.f, den = 0.f;
  for (int i = 0; i < c; ++i) {
    int s = bucket[base + i];
    float e = elg[((size_t)t * N_NODES + s) * 4 + h] + erh;
    e = (e > 0.f) ? e : 0.2f * e;
    float w = __expf(e);
    unsigned int u = ftu[((size_t)t * N_NODES + s) * 64 + lane];
    float fx = __uint_as_float(u << 16);
    float fy = __uint_as_float(u & 0xFFFF0000u);
    ax += w * fx; ay += w * fy; den += w;
  }
  float inv = (c > 0) ? 1.f / den : 0.f;
  *(float2*)(agg + (size_t)n * 256 + slot * 128 + lane * 2) = make_float2(ax * inv, ay * inv);
}

// K4: merge GEMM out[n][j] = agg[n][:] @ Wm + bm. 16 nodes/block.
__global__ __launch_bounds__(256) void k_merge(const float* __restrict__ agg,
    const float* __restrict__ Wm, const float* __restrict__ bm, float* __restrict__ out)
{
  __shared__ __align__(16) float Wl[256 * 32];
  __shared__ __align__(16) float Al[16 * 260];             // +4 pad: banks (4n+k)%32, 2-way max
  int n0 = blockIdx.x * 16;
  int tid = threadIdx.x;
  for (int i = tid; i < 2048; i += 256) ((float4*)Wl)[i] = ((const float4*)Wm)[i];
  for (int i = tid; i < 1024; i += 256) {
    int r = i >> 6, c4 = (i & 63) << 2;
    *(float4*)&Al[r * 260 + c4] = *(const float4*)(agg + (size_t)(n0 + r) * 256 + c4);
  }
  __syncthreads();
  int nn = tid >> 4, j0 = (tid & 15) << 1;
  float s0 = bm[j0], s1 = bm[j0 + 1];
  const float* ar = &Al[nn * 260];
#pragma unroll 4
  for (int k = 0; k < 256; ++k) {
    float a = ar[k];
    float2 w = *(const float2*)&Wl[k * 32 + j0];
    s0 += a * w.x; s1 += a * w.y;
  }
  *(float2*)(out + (size_t)(n0 + nn) * 32 + j0) = make_float2(s0, s1);
}

extern "C" void kernel_launch(void* const* d_in, const int* in_sizes, int n_in,
                              void* d_out, int out_size, void* d_ws, size_t ws_size,
                              hipStream_t stream)
{
  const float* feat = (const float*)d_in[0];
  const int*   src  = (const int*)d_in[1];
  const int*   dst  = (const int*)d_in[2];
  // d_in[3] = is_b, derivable as (n >= 50000); unused
  const float* W    = (const float*)d_in[4];
  const float* al   = (const float*)d_in[5];
  const float* ar   = (const float*)d_in[6];
  const float* Wm   = (const float*)d_in[7];
  const float* bm   = (const float*)d_in[8];
  float* out = (float*)d_out;
  (void)in_sizes; (void)n_in; (void)out_size; (void)ws_size;

  char* w = (char*)d_ws;
  size_t o = 0;
  auto take = [&](size_t bytes) -> void* {
    void* p = w + o;
    o += (bytes + 255) & ~(size_t)255;
    return p;
  };
  unsigned short* Btg = (unsigned short*)take((size_t)N_T * BCOLS * D_IN * 2); // 147 KB
  unsigned short* ftg = (unsigned short*)take((size_t)N_T * N_NODES * HF * 2); // 102.4 MB
  float* elg   = (float*)take((size_t)N_T * N_NODES * 4 * 4);                  // 6.4 MB
  float* erg   = (float*)take((size_t)N_T * N_NODES * 4 * 4);                  // 6.4 MB
  int*   cntb  = (int*)take((size_t)TN * 4);                                   // 1.6 MB
  int*   ofs   = (int*)take((size_t)TN * 4);
  int*   cur   = (int*)take((size_t)TN * 4);
  int*   bsum  = (int*)take(4096);
  int*   bucket= (int*)take((size_t)TE * 4);                                   // 8 MB
  float* agg   = (float*)take((size_t)N_NODES * 256 * 4);                      // 102.4 MB
  // total ~230 MB of workspace

  hipMemsetAsync(cntb, 0, (size_t)TN * 4, stream);
  hipMemsetAsync(cur,  0, (size_t)TN * 4, stream);

  k_prepB<<<2, 256, 0, stream>>>(W, al, ar, Btg);
  k_proj<<<dim3(1563, 4), 256, 0, stream>>>(feat, Btg, ftg, elg, erg);
  k_hist<<<(TE + 255) / 256, 256, 0, stream>>>(dst, cntb);
  k_scan1<<<NB1, 256, 0, stream>>>(cntb, ofs, bsum);
  k_scan2<<<1, 512, 0, stream>>>(bsum);
  k_scan3<<<NB1, 256, 0, stream>>>(ofs, bsum);
  k_scatter<<<(TE + 255) / 256, 256, 0, stream>>>(src, dst, ofs, cur, bucket);
  k_gather<<<50000, 256, 0, stream>>>(bucket, ofs, cntb, (const unsigned int*)ftg, elg, erg, agg);
  k_merge<<<6250, 256, 0, stream>>>(agg, Wm, bm, out);
}

// Round 2
// 332.935 us; speedup vs baseline: 1.2960x; 1.2960x over previous
//
#include <hip/hip_runtime.h>

typedef short short8 __attribute__((ext_vector_type(8)));
typedef float f32x4 __attribute__((ext_vector_type(4)));

#define N_NODES 100000
#define N_A     50000
#define N_EDGES 500000
#define N_T     4
#define D_IN    128
#define HF      128
#define BCOLS   144                  // 128 ft cols + 4 el + 4 er + 8 zero pad
#define TN      (N_T * N_NODES)
#define TE      (N_T * N_EDGES)
#define NB1     ((TN + 1023) / 1024) // 391 scan blocks

__device__ __forceinline__ unsigned short f2b(float f) {
  unsigned int u = __float_as_uint(f);
  u += 0x7FFFu + ((u >> 16) & 1u);
  return (unsigned short)(u >> 16);
}
__device__ __forceinline__ float blo(unsigned int u) { return __uint_as_float(u << 16); }
__device__ __forceinline__ float bhi(unsigned int u) { return __uint_as_float(u & 0xFFFF0000u); }

// K0a: build Bt[t][144][128] bf16 (column-major B): rows 0..127 = W[t][:,j],
// 128+h = W@attn_l[h], 132+h = W@attn_r[h], 136.. = 0
__global__ __launch_bounds__(256) void k_prepB(const float* __restrict__ W,
    const float* __restrict__ al, const float* __restrict__ ar,
    unsigned short* __restrict__ Bt)
{
  int idx = blockIdx.x * 256 + threadIdx.x;
  if (idx >= N_T * D_IN) return;
  int t = idx >> 7, k = idx & 127;
  const float* Wr = W + ((size_t)t * D_IN + k) * HF;
  unsigned short* o = Bt + (size_t)t * BCOLS * D_IN;
  for (int j = 0; j < HF; ++j) o[j * D_IN + k] = f2b(Wr[j]);
  for (int h = 0; h < 4; ++h) {
    float sl = 0.f, sr = 0.f;
    const float* alh = al + (t * 4 + h) * 32;
    const float* arh = ar + (t * 4 + h) * 32;
    for (int f = 0; f < 32; ++f) { float w = Wr[h * 32 + f]; sl += w * alh[f]; sr += w * arh[f]; }
    o[(128 + h) * D_IN + k] = f2b(sl);
    o[(132 + h) * D_IN + k] = f2b(sr);
  }
  for (int j = 136; j < 144; ++j) o[j * D_IN + k] = 0;
}

// K0b: WmT[j][k] bf16 (column-major merge weights for MFMA B-side)
__global__ __launch_bounds__(256) void k_prepWm(const float* __restrict__ Wm,
    unsigned short* __restrict__ WmT)
{
  int idx = blockIdx.x * 256 + threadIdx.x;
  if (idx >= 256 * 32) return;
  int k = idx >> 5, j = idx & 31;
  WmT[j * 256 + k] = f2b(Wm[idx]);
}

// K1: projection GEMM, feat read ONCE per block; loop over 4 types with
// A-fragments held in registers. Writes ft (bf16) + el/er (f32).
__global__ __launch_bounds__(256) void k_proj(const float* __restrict__ feat,
    const unsigned short* __restrict__ Btg,
    unsigned short* __restrict__ ftg,
    float* __restrict__ elg, float* __restrict__ erg)
{
  __shared__ __align__(16) unsigned short As[64 * 136];
  __shared__ __align__(16) unsigned short Bs[144 * 136];
  __shared__ __align__(16) unsigned short Cs[64 * 136];
  const int row0 = blockIdx.x * 64;
  const int tid = threadIdx.x;

  for (int i = tid; i < 64 * 32; i += 256) {               // stage A: f32 -> bf16
    int r = i >> 5, c4 = (i & 31) << 2;
    int row = row0 + r;
    float4 v = make_float4(0.f, 0.f, 0.f, 0.f);
    if (row < N_NODES) v = *(const float4*)(feat + (size_t)row * D_IN + c4);
    unsigned int u01 = (unsigned int)f2b(v.x) | ((unsigned int)f2b(v.y) << 16);
    unsigned int u23 = (unsigned int)f2b(v.z) | ((unsigned int)f2b(v.w) << 16);
    *(uint2*)&As[r * 136 + c4] = make_uint2(u01, u23);
  }
  __syncthreads();

  const int wave = tid >> 6, lane = tid & 63;
  const int l15 = lane & 15, lk = (lane >> 4) * 8;
  const int wrow = wave * 16;
  short8 a[4];
#pragma unroll
  for (int kt = 0; kt < 4; ++kt)
    a[kt] = *(const short8*)&As[(wrow + l15) * 136 + kt * 32 + lk];

  for (int t = 0; t < N_T; ++t) {
    const uint4* bsrc = (const uint4*)(Btg + (size_t)t * BCOLS * D_IN);
    for (int i = tid; i < 144 * 16; i += 256) {
      int r = i >> 4, c = i & 15;
      *(uint4*)&Bs[r * 136 + c * 8] = bsrc[r * 16 + c];
    }
    __syncthreads();

    f32x4 acc[9];
#pragma unroll
    for (int ct = 0; ct < 9; ++ct) {
      f32x4 c = {0.f, 0.f, 0.f, 0.f};
#pragma unroll
      for (int kt = 0; kt < 4; ++kt) {
        short8 b = *(const short8*)&Bs[(ct * 16 + l15) * 136 + kt * 32 + lk];
        c = __builtin_amdgcn_mfma_f32_16x16x32_bf16(a[kt], b, c, 0, 0, 0);
      }
      acc[ct] = c;
    }

    if (l15 < 8) {                                         // el/er from col-tile 8
#pragma unroll
      for (int r = 0; r < 4; ++r) {
        int row = row0 + wrow + (lane >> 4) * 4 + r;
        if (row < N_NODES) {
          float v = acc[8][r];
          if (l15 < 4) elg[((size_t)t * N_NODES + row) * 4 + l15] = v;
          else         erg[((size_t)t * N_NODES + row) * 4 + (l15 - 4)] = v;
        }
      }
    }
#pragma unroll
    for (int ct = 0; ct < 8; ++ct) {                       // stage C into Cs
#pragma unroll
      for (int r = 0; r < 4; ++r) {
        int rr = wrow + (lane >> 4) * 4 + r;
        Cs[rr * 136 + ct * 16 + l15] = f2b(acc[ct][r]);
      }
    }
    __syncthreads();
    for (int i = tid; i < 64 * 16; i += 256) {             // coalesced ft write-out
      int r = i >> 4, c = i & 15;
      int row = row0 + r;
      if (row < N_NODES)
        *(uint4*)(ftg + ((size_t)t * N_NODES + row) * HF + c * 8) = *(const uint4*)&Cs[r * 136 + c * 8];
    }
    // next t's Bs staging writes Bs (mfma reads done pre-sync); Cs writes of
    // next t happen only after its own __syncthreads -> no extra barrier needed
  }
}

// K2: counting sort of kept edges by (t,dst)
__global__ __launch_bounds__(256) void k_hist(const int* __restrict__ dst, int* __restrict__ cnt) {
  int idx = blockIdx.x * 256 + threadIdx.x;
  if (idx >= TE) return;
  int t = idx / N_EDGES;
  int d = dst[idx];
  bool keep = (t < 2) ? (d < N_A) : (d >= N_A);
  if (keep) atomicAdd(&cnt[t * N_NODES + d], 1);
}

__global__ __launch_bounds__(256) void k_scan1(const int* __restrict__ cnt,
    int* __restrict__ ofs, int* __restrict__ bsum) {
  __shared__ int ts[256];
  int b = blockIdx.x, t = threadIdx.x;
  int base = b * 1024 + t * 4;
  int v0 = 0, v1 = 0, v2 = 0, v3 = 0;
  if (base + 0 < TN) v0 = cnt[base + 0];
  if (base + 1 < TN) v1 = cnt[base + 1];
  if (base + 2 < TN) v2 = cnt[base + 2];
  if (base + 3 < TN) v3 = cnt[base + 3];
  int s = v0 + v1 + v2 + v3;
  ts[t] = s;
  __syncthreads();
  for (int o = 1; o < 256; o <<= 1) {
    int x = (t >= o) ? ts[t - o] : 0;
    __syncthreads();
    ts[t] += x;
    __syncthreads();
  }
  int run = ts[t] - s;
  if (base + 0 < TN) ofs[base + 0] = run; run += v0;
  if (base + 1 < TN) ofs[base + 1] = run; run += v1;
  if (base + 2 < TN) ofs[base + 2] = run; run += v2;
  if (base + 3 < TN) ofs[base + 3] = run;
  if (t == 255) bsum[b] = ts[255];
}

__global__ __launch_bounds__(512) void k_scan2(int* __restrict__ bsum) {
  __shared__ int ts[512];
  int t = threadIdx.x;
  int v = (t < NB1) ? bsum[t] : 0;
  ts[t] = v;
  __syncthreads();
  for (int o = 1; o < 512; o <<= 1) {
    int x = (t >= o) ? ts[t - o] : 0;
    __syncthreads();
    ts[t] += x;
    __syncthreads();
  }
  if (t < NB1) bsum[t] = ts[t] - v;
}

__global__ __launch_bounds__(256) void k_scan3(int* __restrict__ ofs, const int* __restrict__ bsum) {
  int b = blockIdx.x;
  int add = bsum[b];
  int base = b * 1024;
  for (int i = threadIdx.x; i < 1024; i += 256) {
    int j = base + i;
    if (j < TN) ofs[j] += add;
  }
}

// K3: scatter kept edges AND precompute softmax weights w[h]=exp(leaky(el+er))
__global__ __launch_bounds__(256) void k_scatter(const int* __restrict__ src, const int* __restrict__ dst,
    const int* __restrict__ ofs, int* __restrict__ cur,
    const float* __restrict__ elg, const float* __restrict__ erg,
    int* __restrict__ bsrc, float4* __restrict__ bw) {
  int idx = blockIdx.x * 256 + threadIdx.x;
  if (idx >= TE) return;
  int t = idx / N_EDGES;
  int d = dst[idx];
  bool keep = (t < 2) ? (d < N_A) : (d >= N_A);
  if (!keep) return;
  int s = src[idx];
  int key = t * N_NODES + d;
  int p = ofs[key] + atomicAdd(&cur[key], 1);
  bsrc[p] = s;
  float4 el4 = *(const float4*)(elg + ((size_t)t * N_NODES + s) * 4);
  float4 er4 = *(const float4*)(erg + ((size_t)t * N_NODES + d) * 4);
  float4 w;
  float e;
  e = el4.x + er4.x; w.x = __expf(e > 0.f ? e : 0.2f * e);
  e = el4.y + er4.y; w.y = __expf(e > 0.f ? e : 0.2f * e);
  e = el4.z + er4.z; w.z = __expf(e > 0.f ? e : 0.2f * e);
  e = el4.w + er4.w; w.w = __expf(e > 0.f ? e : 0.2f * e);
  bw[p] = w;
}

// K4: gather, 4 edges per iteration (16 lanes/edge, uint4 ft loads), weights
// precomputed; cross-group reduce via shfl_xor; bf16 agg output.
__global__ __launch_bounds__(256) void k_gather(const int* __restrict__ bsrc,
    const float* __restrict__ bw,
    const int* __restrict__ ofs, const int* __restrict__ cnt,
    const uint4* __restrict__ ftu, uint4* __restrict__ aggb)
{
  int wid = blockIdx.x * 4 + (threadIdx.x >> 6);
  int lane = threadIdx.x & 63;
  int n = wid >> 1, slot = wid & 1;
  if (n >= N_NODES) return;
  int t = slot + ((n >= N_A) ? 2 : 0);
  int key = t * N_NODES + n;
  int base = ofs[key], c = cnt[key];
  int g = lane >> 4, l15 = lane & 15, hsel = l15 >> 2;
  float a0 = 0.f, a1 = 0.f, a2 = 0.f, a3 = 0.f, a4 = 0.f, a5 = 0.f, a6 = 0.f, a7 = 0.f;
  float den = 0.f;
  int tbase = t * N_NODES;
  for (int i0 = 0; i0 < c; i0 += 4) {
    int j = i0 + g;
    float w = 0.f; int s = 0;
    if (j < c) { int e = base + j; s = bsrc[e]; w = bw[e * 4 + hsel]; }
    uint4 u = ftu[(size_t)(tbase + s) * 16 + l15];
    den += w;
    a0 += w * blo(u.x); a1 += w * bhi(u.x);
    a2 += w * blo(u.y); a3 += w * bhi(u.y);
    a4 += w * blo(u.z); a5 += w * bhi(u.z);
    a6 += w * blo(u.w); a7 += w * bhi(u.w);
  }
  // reduce across the 4 sixteen-lane groups (lane bits 4,5)
  a0 += __shfl_xor(a0, 16); a0 += __shfl_xor(a0, 32);
  a1 += __shfl_xor(a1, 16); a1 += __shfl_xor(a1, 32);
  a2 += __shfl_xor(a2, 16); a2 += __shfl_xor(a2, 32);
  a3 += __shfl_xor(a3, 16); a3 += __shfl_xor(a3, 32);
  a4 += __shfl_xor(a4, 16); a4 += __shfl_xor(a4, 32);
  a5 += __shfl_xor(a5, 16); a5 += __shfl_xor(a5, 32);
  a6 += __shfl_xor(a6, 16); a6 += __shfl_xor(a6, 32);
  a7 += __shfl_xor(a7, 16); a7 += __shfl_xor(a7, 32);
  den += __shfl_xor(den, 16); den += __shfl_xor(den, 32);
  if (lane < 16) {
    float inv = (c > 0) ? 1.f / den : 0.f;
    uint4 o;
    o.x = (unsigned int)f2b(a0 * inv) | ((unsigned int)f2b(a1 * inv) << 16);
    o.y = (unsigned int)f2b(a2 * inv) | ((unsigned int)f2b(a3 * inv) << 16);
    o.z = (unsigned int)f2b(a4 * inv) | ((unsigned int)f2b(a5 * inv) << 16);
    o.w = (unsigned int)f2b(a6 * inv) | ((unsigned int)f2b(a7 * inv) << 16);
    aggb[(size_t)n * 32 + slot * 16 + l15] = o;
  }
}

// K5: merge GEMM via MFMA. 64 nodes/block, out = agg(bf16) @ Wm + bm.
__global__ __launch_bounds__(256) void k_merge(const unsigned short* __restrict__ aggb,
    const unsigned short* __restrict__ WmT, const float* __restrict__ bm,
    float* __restrict__ out)
{
  __shared__ __align__(16) unsigned short Al[64 * 264];
  __shared__ __align__(16) unsigned short Bl[32 * 264];
  int n0 = blockIdx.x * 64;
  int tid = threadIdx.x;
  const uint4* asrc = (const uint4*)(aggb + (size_t)n0 * 256);
  for (int i = tid; i < 2048; i += 256) {
    int r = i >> 5, c = i & 31;
    *(uint4*)&Al[r * 264 + c * 8] = asrc[r * 32 + c];
  }
  for (int i = tid; i < 1024; i += 256) {
    int r = i >> 5, c = i & 31;
    *(uint4*)&Bl[r * 264 + c * 8] = ((const uint4*)WmT)[r * 32 + c];
  }
  __syncthreads();
  int wave = tid >> 6, lane = tid & 63;
  int l15 = lane & 15, lk = (lane >> 4) * 8;
  short8 a[8];
#pragma unroll
  for (int kt = 0; kt < 8; ++kt)
    a[kt] = *(const short8*)&Al[(wave * 16 + l15) * 264 + kt * 32 + lk];
  f32x4 acc0 = {0.f, 0.f, 0.f, 0.f}, acc1 = {0.f, 0.f, 0.f, 0.f};
#pragma unroll
  for (int kt = 0; kt < 8; ++kt) {
    short8 b0 = *(const short8*)&Bl[l15 * 264 + kt * 32 + lk];
    short8 b1 = *(const short8*)&Bl[(16 + l15) * 264 + kt * 32 + lk];
    acc0 = __builtin_amdgcn_mfma_f32_16x16x32_bf16(a[kt], b0, acc0, 0, 0, 0);
    acc1 = __builtin_amdgcn_mfma_f32_16x16x32_bf16(a[kt], b1, acc1, 0, 0, 0);
  }
  float bm0 = bm[l15], bm1 = bm[16 + l15];
#pragma unroll
  for (int r = 0; r < 4; ++r) {
    int row = n0 + wave * 16 + (lane >> 4) * 4 + r;
    if (row < N_NODES) {
      out[(size_t)row * 32 + l15] = acc0[r] + bm0;
      out[(size_t)row * 32 + 16 + l15] = acc1[r] + bm1;
    }
  }
}

extern "C" void kernel_launch(void* const* d_in, const int* in_sizes, int n_in,
                              void* d_out, int out_size, void* d_ws, size_t ws_size,
                              hipStream_t stream)
{
  const float* feat = (const float*)d_in[0];
  const int*   src  = (const int*)d_in[1];
  const int*   dst  = (const int*)d_in[2];
  const float* W    = (const float*)d_in[4];
  const float* al   = (const float*)d_in[5];
  const float* ar   = (const float*)d_in[6];
  const float* Wm   = (const float*)d_in[7];
  const float* bm   = (const float*)d_in[8];
  float* out = (float*)d_out;
  (void)in_sizes; (void)n_in; (void)out_size; (void)ws_size;

  char* w = (char*)d_ws;
  size_t o = 0;
  auto take = [&](size_t bytes) -> void* {
    void* p = w + o;
    o += (bytes + 255) & ~(size_t)255;
    return p;
  };
  unsigned short* Btg = (unsigned short*)take((size_t)N_T * BCOLS * D_IN * 2);   // 147 KB
  unsigned short* WmT = (unsigned short*)take((size_t)32 * 256 * 2);             // 16 KB
  unsigned short* ftg = (unsigned short*)take((size_t)N_T * N_NODES * HF * 2);   // 102.4 MB
  float* elg   = (float*)take((size_t)N_T * N_NODES * 4 * 4);                    // 6.4 MB
  float* erg   = (float*)take((size_t)N_T * N_NODES * 4 * 4);                    // 6.4 MB
  int*   cntb  = (int*)take((size_t)TN * 4);                                     // 1.6 MB
  int*   ofs   = (int*)take((size_t)TN * 4);
  int*   cur   = (int*)take((size_t)TN * 4);
  int*   bsum  = (int*)take(4096);
  int*   bsrc  = (int*)take((size_t)TE * 4);                                     // 8 MB
  float* bwgt  = (float*)take((size_t)TE * 16);                                  // 32 MB
  unsigned short* aggb = (unsigned short*)take((size_t)(N_NODES + 64) * 256 * 2);// 51.2 MB

  hipMemsetAsync(cntb, 0, (size_t)TN * 4, stream);
  hipMemsetAsync(cur,  0, (size_t)TN * 4, stream);

  k_prepB<<<2, 256, 0, stream>>>(W, al, ar, Btg);
  k_prepWm<<<32, 256, 0, stream>>>(Wm, WmT);
  k_proj<<<1563, 256, 0, stream>>>(feat, Btg, ftg, elg, erg);
  k_hist<<<(TE + 255) / 256, 256, 0, stream>>>(dst, cntb);
  k_scan1<<<NB1, 256, 0, stream>>>(cntb, ofs, bsum);
  k_scan2<<<1, 512, 0, stream>>>(bsum);
  k_scan3<<<NB1, 256, 0, stream>>>(ofs, bsum);
  k_scatter<<<(TE + 255) / 256, 256, 0, stream>>>(src, dst, ofs, cur, elg, erg, bsrc, (float4*)bwgt);
  k_gather<<<50000, 256, 0, stream>>>(bsrc, bwgt, ofs, cntb, (const uint4*)ftg, (uint4*)aggb);
  k_merge<<<1563, 256, 0, stream>>>(aggb, WmT, bm, out);
}

// Round 3
// 330.627 us; speedup vs baseline: 1.3050x; 1.0070x over previous
//
#include <hip/hip_runtime.h>

typedef short short8 __attribute__((ext_vector_type(8)));
typedef float f32x4 __attribute__((ext_vector_type(4)));

#define N_NODES 100000
#define N_A     50000
#define N_EDGES 500000
#define N_T     4
#define D_IN    128
#define HF      128
#define BCOLS   144                  // 128 ft cols + 4 el + 4 er + 8 zero pad
#define TN      (N_T * N_NODES)
#define TE      (N_T * N_EDGES)
#define NB1     ((TN + 1023) / 1024) // 391 scan blocks
#define NPB     782                  // proj blocks: 782*128 >= 100000

__device__ __forceinline__ unsigned short f2b(float f) {
  unsigned int u = __float_as_uint(f);
  u += 0x7FFFu + ((u >> 16) & 1u);
  return (unsigned short)(u >> 16);
}
__device__ __forceinline__ float blo(unsigned int u) { return __uint_as_float(u << 16); }
__device__ __forceinline__ float bhi(unsigned int u) { return __uint_as_float(u & 0xFFFF0000u); }
__device__ __forceinline__ float b2f(unsigned short u) { return __uint_as_float((unsigned int)u << 16); }

// K0a: build Bt[t][144][128] bf16 (column-major B): rows 0..127 = W[t][:,j],
// 128+h = W@attn_l[h], 132+h = W@attn_r[h], 136.. = 0
__global__ __launch_bounds__(256) void k_prepB(const float* __restrict__ W,
    const float* __restrict__ al, const float* __restrict__ ar,
    unsigned short* __restrict__ Bt)
{
  int idx = blockIdx.x * 256 + threadIdx.x;
  if (idx >= N_T * D_IN) return;
  int t = idx >> 7, k = idx & 127;
  const float* Wr = W + ((size_t)t * D_IN + k) * HF;
  unsigned short* o = Bt + (size_t)t * BCOLS * D_IN;
  for (int j = 0; j < HF; ++j) o[j * D_IN + k] = f2b(Wr[j]);
  for (int h = 0; h < 4; ++h) {
    float sl = 0.f, sr = 0.f;
    const float* alh = al + (t * 4 + h) * 32;
    const float* arh = ar + (t * 4 + h) * 32;
    for (int f = 0; f < 32; ++f) { float w = Wr[h * 32 + f]; sl += w * alh[f]; sr += w * arh[f]; }
    o[(128 + h) * D_IN + k] = f2b(sl);
    o[(132 + h) * D_IN + k] = f2b(sr);
  }
  for (int j = 136; j < 144; ++j) o[j * D_IN + k] = 0;
}

// K0b: WmT[j][k] bf16 (column-major merge weights for MFMA B-side)
__global__ __launch_bounds__(256) void k_prepWm(const float* __restrict__ Wm,
    unsigned short* __restrict__ WmT)
{
  int idx = blockIdx.x * 256 + threadIdx.x;
  if (idx >= 256 * 32) return;
  int k = idx >> 5, j = idx & 31;
  WmT[j * 256 + k] = f2b(Wm[idx]);
}

// K1: projection GEMM, barrier-free. Each wave owns 32 rows (2 row-tiles);
// A-frags from global feat (f32->bf16 in reg), B-frags from global Btg (L2),
// only Cs (per-wave, private) in LDS for the output transpose.
__global__ __launch_bounds__(256) void k_proj(const float* __restrict__ feat,
    const unsigned short* __restrict__ Btg,
    unsigned short* __restrict__ ftg,
    float* __restrict__ elg, float* __restrict__ erg)
{
  __shared__ __align__(16) unsigned short Cs[128 * 136];   // 34.8 KB -> 4 blocks/CU
  const int tid = threadIdx.x;
  const int wave = tid >> 6, lane = tid & 63;
  const int l15 = lane & 15, g = lane >> 4, lk = g * 8;
  const int wrow0 = blockIdx.x * 128 + wave * 32;
  if (wrow0 >= N_NODES) return;                            // no barriers -> safe
  unsigned short* Cw = Cs + wave * 32 * 136;

  // A fragments: rt in {0,1}, kt in {0..3}; row = wrow0+rt*16+l15, k = kt*32+lk+j
  short8 a[2][4];
#pragma unroll
  for (int rt = 0; rt < 2; ++rt) {
    int row = wrow0 + rt * 16 + l15;
    bool ok = row < N_NODES;
    const float* fr = feat + (size_t)(ok ? row : 0) * D_IN;
#pragma unroll
    for (int kt = 0; kt < 4; ++kt) {
      float4 v0 = *(const float4*)(fr + kt * 32 + lk);
      float4 v1 = *(const float4*)(fr + kt * 32 + lk + 4);
      short8 s;
      s[0] = (short)f2b(ok ? v0.x : 0.f); s[1] = (short)f2b(ok ? v0.y : 0.f);
      s[2] = (short)f2b(ok ? v0.z : 0.f); s[3] = (short)f2b(ok ? v0.w : 0.f);
      s[4] = (short)f2b(ok ? v1.x : 0.f); s[5] = (short)f2b(ok ? v1.y : 0.f);
      s[6] = (short)f2b(ok ? v1.z : 0.f); s[7] = (short)f2b(ok ? v1.w : 0.f);
      a[rt][kt] = s;
    }
  }

  for (int t = 0; t < N_T; ++t) {
    const unsigned short* Bt = Btg + (size_t)t * BCOLS * D_IN;
#pragma unroll
    for (int ct = 0; ct < 9; ++ct) {
      short8 b[4];
#pragma unroll
      for (int kt = 0; kt < 4; ++kt)
        b[kt] = *(const short8*)(Bt + (size_t)(ct * 16 + l15) * D_IN + kt * 32 + lk);
      f32x4 acc0 = {0.f, 0.f, 0.f, 0.f}, acc1 = {0.f, 0.f, 0.f, 0.f};
#pragma unroll
      for (int kt = 0; kt < 4; ++kt) {
        acc0 = __builtin_amdgcn_mfma_f32_16x16x32_bf16(a[0][kt], b[kt], acc0, 0, 0, 0);
        acc1 = __builtin_amdgcn_mfma_f32_16x16x32_bf16(a[1][kt], b[kt], acc1, 0, 0, 0);
      }
      if (ct == 8) {                                       // el/er columns
        if (l15 < 8) {
#pragma unroll
          for (int rt = 0; rt < 2; ++rt) {
            f32x4 A = (rt == 0) ? acc0 : acc1;
#pragma unroll
            for (int r = 0; r < 4; ++r) {
              int row = wrow0 + rt * 16 + g * 4 + r;
              if (row < N_NODES) {
                float v = A[r];
                if (l15 < 4) elg[((size_t)t * N_NODES + row) * 4 + l15] = v;
                else         erg[((size_t)t * N_NODES + row) * 4 + (l15 - 4)] = v;
              }
            }
          }
        }
      } else {                                             // stage into per-wave Cs
#pragma unroll
        for (int r = 0; r < 4; ++r) {
          Cw[(g * 4 + r) * 136 + ct * 16 + l15]      = f2b(acc0[r]);
          Cw[(16 + g * 4 + r) * 136 + ct * 16 + l15] = f2b(acc1[r]);
        }
      }
    }
    // coalesced ft write-out (wave-private Cs -> ordering via lgkmcnt only)
#pragma unroll
    for (int i = 0; i < 8; ++i) {
      int idx = i * 64 + lane;
      int r = idx >> 4, c = idx & 15;
      int row = wrow0 + r;
      if (row < N_NODES)
        *(uint4*)(ftg + ((size_t)t * N_NODES + row) * HF + c * 8) = *(const uint4*)&Cw[r * 136 + c * 8];
    }
  }
}

// K2: counting sort of kept edges by (t,dst)
__global__ __launch_bounds__(256) void k_hist(const int* __restrict__ dst, int* __restrict__ cnt) {
  int idx = blockIdx.x * 256 + threadIdx.x;
  if (idx >= TE) return;
  int t = idx / N_EDGES;
  int d = dst[idx];
  bool keep = (t < 2) ? (d < N_A) : (d >= N_A);
  if (keep) atomicAdd(&cnt[t * N_NODES + d], 1);
}

__global__ __launch_bounds__(256) void k_scan1(const int* __restrict__ cnt,
    int* __restrict__ ofs, int* __restrict__ bsum) {
  __shared__ int ts[256];
  int b = blockIdx.x, t = threadIdx.x;
  int base = b * 1024 + t * 4;
  int v0 = 0, v1 = 0, v2 = 0, v3 = 0;
  if (base + 0 < TN) v0 = cnt[base + 0];
  if (base + 1 < TN) v1 = cnt[base + 1];
  if (base + 2 < TN) v2 = cnt[base + 2];
  if (base + 3 < TN) v3 = cnt[base + 3];
  int s = v0 + v1 + v2 + v3;
  ts[t] = s;
  __syncthreads();
  for (int o = 1; o < 256; o <<= 1) {
    int x = (t >= o) ? ts[t - o] : 0;
    __syncthreads();
    ts[t] += x;
    __syncthreads();
  }
  int run = ts[t] - s;
  if (base + 0 < TN) ofs[base + 0] = run; run += v0;
  if (base + 1 < TN) ofs[base + 1] = run; run += v1;
  if (base + 2 < TN) ofs[base + 2] = run; run += v2;
  if (base + 3 < TN) ofs[base + 3] = run;
  if (t == 255) bsum[b] = ts[255];
}

__global__ __launch_bounds__(512) void k_scan2(int* __restrict__ bsum) {
  __shared__ int ts[512];
  int t = threadIdx.x;
  int v = (t < NB1) ? bsum[t] : 0;
  ts[t] = v;
  __syncthreads();
  for (int o = 1; o < 512; o <<= 1) {
    int x = (t >= o) ? ts[t - o] : 0;
    __syncthreads();
    ts[t] += x;
    __syncthreads();
  }
  if (t < NB1) bsum[t] = ts[t] - v;
}

__global__ __launch_bounds__(256) void k_scan3(int* __restrict__ ofs, const int* __restrict__ bsum) {
  int b = blockIdx.x;
  int add = bsum[b];
  int base = b * 1024;
  for (int i = threadIdx.x; i < 1024; i += 256) {
    int j = base + i;
    if (j < TN) ofs[j] += add;
  }
}

// K3: scatter kept edges AND precompute softmax weights w[h]=exp(leaky(el+er)), bf16-packed
__global__ __launch_bounds__(256) void k_scatter(const int* __restrict__ src, const int* __restrict__ dst,
    const int* __restrict__ ofs, int* __restrict__ cur,
    const float* __restrict__ elg, const float* __restrict__ erg,
    int* __restrict__ bsrc, uint2* __restrict__ bw) {
  int idx = blockIdx.x * 256 + threadIdx.x;
  if (idx >= TE) return;
  int t = idx / N_EDGES;
  int d = dst[idx];
  bool keep = (t < 2) ? (d < N_A) : (d >= N_A);
  if (!keep) return;
  int s = src[idx];
  int key = t * N_NODES + d;
  int p = ofs[key] + atomicAdd(&cur[key], 1);
  bsrc[p] = s;
  float4 el4 = *(const float4*)(elg + ((size_t)t * N_NODES + s) * 4);
  float4 er4 = *(const float4*)(erg + ((size_t)t * N_NODES + d) * 4);
  float e, w0, w1, w2, w3;
  e = el4.x + er4.x; w0 = __expf(e > 0.f ? e : 0.2f * e);
  e = el4.y + er4.y; w1 = __expf(e > 0.f ? e : 0.2f * e);
  e = el4.z + er4.z; w2 = __expf(e > 0.f ? e : 0.2f * e);
  e = el4.w + er4.w; w3 = __expf(e > 0.f ? e : 0.2f * e);
  uint2 u;
  u.x = (unsigned int)f2b(w0) | ((unsigned int)f2b(w1) << 16);
  u.y = (unsigned int)f2b(w2) | ((unsigned int)f2b(w3) << 16);
  bw[p] = u;
}

// K4: gather, 4 edges per iteration (16 lanes/edge, uint4 ft loads), weights
// precomputed (bf16); cross-group reduce via shfl_xor; bf16 agg output.
__global__ __launch_bounds__(256) void k_gather(const int* __restrict__ bsrc,
    const unsigned short* __restrict__ bwh,
    const int* __restrict__ ofs, const int* __restrict__ cnt,
    const uint4* __restrict__ ftu, uint4* __restrict__ aggb)
{
  int wid = blockIdx.x * 4 + (threadIdx.x >> 6);
  int lane = threadIdx.x & 63;
  int n = wid >> 1, slot = wid & 1;
  if (n >= N_NODES) return;
  int t = slot + ((n >= N_A) ? 2 : 0);
  int key = t * N_NODES + n;
  int base = ofs[key], c = cnt[key];
  int g = lane >> 4, l15 = lane & 15, hsel = l15 >> 2;
  float a0 = 0.f, a1 = 0.f, a2 = 0.f, a3 = 0.f, a4 = 0.f, a5 = 0.f, a6 = 0.f, a7 = 0.f;
  float den = 0.f;
  int tbase = t * N_NODES;
  for (int i0 = 0; i0 < c; i0 += 4) {
    int j = i0 + g;
    float w = 0.f; int s = 0;
    if (j < c) { int e = base + j; s = bsrc[e]; w = b2f(bwh[e * 4 + hsel]); }
    uint4 u = ftu[(size_t)(tbase + s) * 16 + l15];
    den += w;
    a0 += w * blo(u.x); a1 += w * bhi(u.x);
    a2 += w * blo(u.y); a3 += w * bhi(u.y);
    a4 += w * blo(u.z); a5 += w * bhi(u.z);
    a6 += w * blo(u.w); a7 += w * bhi(u.w);
  }
  a0 += __shfl_xor(a0, 16); a0 += __shfl_xor(a0, 32);
  a1 += __shfl_xor(a1, 16); a1 += __shfl_xor(a1, 32);
  a2 += __shfl_xor(a2, 16); a2 += __shfl_xor(a2, 32);
  a3 += __shfl_xor(a3, 16); a3 += __shfl_xor(a3, 32);
  a4 += __shfl_xor(a4, 16); a4 += __shfl_xor(a4, 32);
  a5 += __shfl_xor(a5, 16); a5 += __shfl_xor(a5, 32);
  a6 += __shfl_xor(a6, 16); a6 += __shfl_xor(a6, 32);
  a7 += __shfl_xor(a7, 16); a7 += __shfl_xor(a7, 32);
  den += __shfl_xor(den, 16); den += __shfl_xor(den, 32);
  if (lane < 16) {
    float inv = (c > 0) ? 1.f / den : 0.f;
    uint4 o;
    o.x = (unsigned int)f2b(a0 * inv) | ((unsigned int)f2b(a1 * inv) << 16);
    o.y = (unsigned int)f2b(a2 * inv) | ((unsigned int)f2b(a3 * inv) << 16);
    o.z = (unsigned int)f2b(a4 * inv) | ((unsigned int)f2b(a5 * inv) << 16);
    o.w = (unsigned int)f2b(a6 * inv) | ((unsigned int)f2b(a7 * inv) << 16);
    aggb[(size_t)n * 32 + slot * 16 + l15] = o;
  }
}

// K5: merge GEMM via MFMA. 64 nodes/block, out = agg(bf16) @ Wm + bm.
__global__ __launch_bounds__(256) void k_merge(const unsigned short* __restrict__ aggb,
    const unsigned short* __restrict__ WmT, const float* __restrict__ bm,
    float* __restrict__ out)
{
  __shared__ __align__(16) unsigned short Al[64 * 264];
  __shared__ __align__(16) unsigned short Bl[32 * 264];
  int n0 = blockIdx.x * 64;
  int tid = threadIdx.x;
  const uint4* asrc = (const uint4*)(aggb + (size_t)n0 * 256);
  for (int i = tid; i < 2048; i += 256) {
    int r = i >> 5, c = i & 31;
    *(uint4*)&Al[r * 264 + c * 8] = asrc[r * 32 + c];
  }
  for (int i = tid; i < 1024; i += 256) {
    int r = i >> 5, c = i & 31;
    *(uint4*)&Bl[r * 264 + c * 8] = ((const uint4*)WmT)[r * 32 + c];
  }
  __syncthreads();
  int wave = tid >> 6, lane = tid & 63;
  int l15 = lane & 15, lk = (lane >> 4) * 8;
  short8 a[8];
#pragma unroll
  for (int kt = 0; kt < 8; ++kt)
    a[kt] = *(const short8*)&Al[(wave * 16 + l15) * 264 + kt * 32 + lk];
  f32x4 acc0 = {0.f, 0.f, 0.f, 0.f}, acc1 = {0.f, 0.f, 0.f, 0.f};
#pragma unroll
  for (int kt = 0; kt < 8; ++kt) {
    short8 b0 = *(const short8*)&Bl[l15 * 264 + kt * 32 + lk];
    short8 b1 = *(const short8*)&Bl[(16 + l15) * 264 + kt * 32 + lk];
    acc0 = __builtin_amdgcn_mfma_f32_16x16x32_bf16(a[kt], b0, acc0, 0, 0, 0);
    acc1 = __builtin_amdgcn_mfma_f32_16x16x32_bf16(a[kt], b1, acc1, 0, 0, 0);
  }
  float bm0 = bm[l15], bm1 = bm[16 + l15];
#pragma unroll
  for (int r = 0; r < 4; ++r) {
    int row = n0 + wave * 16 + (lane >> 4) * 4 + r;
    if (row < N_NODES) {
      out[(size_t)row * 32 + l15] = acc0[r] + bm0;
      out[(size_t)row * 32 + 16 + l15] = acc1[r] + bm1;
    }
  }
}

extern "C" void kernel_launch(void* const* d_in, const int* in_sizes, int n_in,
                              void* d_out, int out_size, void* d_ws, size_t ws_size,
                              hipStream_t stream)
{
  const float* feat = (const float*)d_in[0];
  const int*   src  = (const int*)d_in[1];
  const int*   dst  = (const int*)d_in[2];
  const float* W    = (const float*)d_in[4];
  const float* al   = (const float*)d_in[5];
  const float* ar   = (const float*)d_in[6];
  const float* Wm   = (const float*)d_in[7];
  const float* bm   = (const float*)d_in[8];
  float* out = (float*)d_out;
  (void)in_sizes; (void)n_in; (void)out_size; (void)ws_size;

  char* w = (char*)d_ws;
  size_t o = 0;
  auto take = [&](size_t bytes) -> void* {
    void* p = w + o;
    o += (bytes + 255) & ~(size_t)255;
    return p;
  };
  unsigned short* Btg = (unsigned short*)take((size_t)N_T * BCOLS * D_IN * 2);   // 147 KB
  unsigned short* WmT = (unsigned short*)take((size_t)32 * 256 * 2);             // 16 KB
  unsigned short* ftg = (unsigned short*)take((size_t)N_T * N_NODES * HF * 2);   // 102.4 MB
  float* elg   = (float*)take((size_t)N_T * N_NODES * 4 * 4);                    // 6.4 MB
  float* erg   = (float*)take((size_t)N_T * N_NODES * 4 * 4);                    // 6.4 MB
  int*   cntb  = (int*)take((size_t)TN * 4);                                     // 1.6 MB
  int*   ofs   = (int*)take((size_t)TN * 4);
  int*   cur   = (int*)take((size_t)TN * 4);
  int*   bsum  = (int*)take(4096);
  int*   bsrc  = (int*)take((size_t)TE * 4);                                     // 8 MB
  uint2* bwgt  = (uint2*)take((size_t)TE * 8);                                   // 16 MB
  unsigned short* aggb = (unsigned short*)take((size_t)(N_NODES + 64) * 256 * 2);// 51.2 MB

  hipMemsetAsync(cntb, 0, (size_t)TN * 4, stream);
  hipMemsetAsync(cur,  0, (size_t)TN * 4, stream);

  k_prepB<<<2, 256, 0, stream>>>(W, al, ar, Btg);
  k_prepWm<<<32, 256, 0, stream>>>(Wm, WmT);
  k_proj<<<NPB, 256, 0, stream>>>(feat, Btg, ftg, elg, erg);
  k_hist<<<(TE + 255) / 256, 256, 0, stream>>>(dst, cntb);
  k_scan1<<<NB1, 256, 0, stream>>>(cntb, ofs, bsum);
  k_scan2<<<1, 512, 0, stream>>>(bsum);
  k_scan3<<<NB1, 256, 0, stream>>>(ofs, bsum);
  k_scatter<<<(TE + 255) / 256, 256, 0, stream>>>(src, dst, ofs, cur, elg, erg, bsrc, bwgt);
  k_gather<<<50000, 256, 0, stream>>>(bsrc, (const unsigned short*)bwgt, ofs, cntb, (const uint4*)ftg, (uint4*)aggb);
  k_merge<<<1563, 256, 0, stream>>>(aggb, WmT, bm, out);
}

// Round 4
// 280.258 us; speedup vs baseline: 1.5396x; 1.1797x over previous
//
#include <hip/hip_runtime.h>

typedef short short8 __attribute__((ext_vector_type(8)));
typedef float f32x4 __attribute__((ext_vector_type(4)));

#define N_NODES 100000
#define N_A     50000
#define N_EDGES 500000
#define N_T     4
#define D_IN    128
#define HF      128
#define BCOLS   144                  // 128 ft cols + 4 el + 4 er + 8 zero pad
#define TN      (N_T * N_NODES)
#define TE      (N_T * N_EDGES)
#define NB1     ((TN + 1023) / 1024) // 391 scan blocks
#define TILE_E  (BCOLS * D_IN)       // 18432 elems = 36864 B per (t) B-tile

__device__ __forceinline__ unsigned short f2b(float f) {
  unsigned int u = __float_as_uint(f);
  u += 0x7FFFu + ((u >> 16) & 1u);
  return (unsigned short)(u >> 16);
}
__device__ __forceinline__ unsigned int pk2(float lo, float hi) {
  return (unsigned int)f2b(lo) | ((unsigned int)f2b(hi) << 16);
}
__device__ __forceinline__ float blo(unsigned int u) { return __uint_as_float(u << 16); }
__device__ __forceinline__ float bhi(unsigned int u) { return __uint_as_float(u & 0xFFFF0000u); }

// K0a: build Bt[t][144][128] bf16, XOR-SWIZZLED: element (j,k) stored at
// linear index (j*128+k) ^ ((j&7)<<3)  [= byte addr ^ ((row&7)<<4)].
// Rows: 0..127 = W[t][:,j]; 128+h = W@attn_l[h]; 132+h = W@attn_r[h]; 136..143 = 0
__global__ __launch_bounds__(256) void k_prepB(const float* __restrict__ W,
    const float* __restrict__ al, const float* __restrict__ ar,
    unsigned short* __restrict__ Bt)
{
  int idx = blockIdx.x * 256 + threadIdx.x;
  if (idx >= N_T * D_IN) return;
  int t = idx >> 7, k = idx & 127;
  const float* Wr = W + ((size_t)t * D_IN + k) * HF;
  unsigned short* o = Bt + (size_t)t * TILE_E;
  for (int j = 0; j < HF; ++j)
    o[(j * D_IN + k) ^ ((j & 7) << 3)] = f2b(Wr[j]);
  for (int h = 0; h < 4; ++h) {
    float sl = 0.f, sr = 0.f;
    const float* alh = al + (t * 4 + h) * 32;
    const float* arh = ar + (t * 4 + h) * 32;
    for (int f = 0; f < 32; ++f) { float w = Wr[h * 32 + f]; sl += w * alh[f]; sr += w * arh[f]; }
    int jl = 128 + h, jr = 132 + h;
    o[(jl * D_IN + k) ^ ((jl & 7) << 3)] = f2b(sl);
    o[(jr * D_IN + k) ^ ((jr & 7) << 3)] = f2b(sr);
  }
  for (int j = 136; j < 144; ++j)
    o[(j * D_IN + k) ^ ((j & 7) << 3)] = 0;
}

// K0b: WmT[j][kidx] bf16 where kidx = slot*128 + p and p is the PERMUTED ft
// position: col(p) = (p&7)*16 + (p>>3).
__global__ __launch_bounds__(256) void k_prepWm(const float* __restrict__ Wm,
    unsigned short* __restrict__ WmT)
{
  int idx = blockIdx.x * 256 + threadIdx.x;
  if (idx >= 256 * 32) return;
  int kidx = idx >> 5, j = idx & 31;
  int slot = kidx >> 7, p = kidx & 127;
  int col = (p & 7) * 16 + (p >> 3);
  WmT[j * 256 + kidx] = f2b(Wm[(slot * 128 + col) * 32 + j]);
}

// K1: projection GEMM. Block = 64 rows (4 waves x 16 rows), grid 1563.
// A-frags from global feat (f32->bf16 in reg, loaded once). B staged in LDS
// per t (pre-swizzled -> linear copy), read via swizzled ds_read_b128.
// ft written DIRECTLY from accumulators in permuted layout (no transpose).
__global__ __launch_bounds__(256, 4) void k_proj(const float* __restrict__ feat,
    const unsigned short* __restrict__ Btg,
    unsigned short* __restrict__ ftg,
    float* __restrict__ elg, float* __restrict__ erg)
{
  __shared__ __align__(16) unsigned short Bs[TILE_E];      // 36.8 KB -> 4 blocks/CU
  const int tid = threadIdx.x;
  const int wave = tid >> 6, lane = tid & 63;
  const int l15 = lane & 15, g = lane >> 4;
  const int wrow0 = blockIdx.x * 64 + wave * 16;

  // A fragments: row = wrow0 + l15, k = kt*32 + g*8 + j (clamped; stores guarded)
  short8 a[4];
  {
    int row = wrow0 + l15;
    const float* fr = feat + (size_t)(row < N_NODES ? row : N_NODES - 1) * D_IN;
#pragma unroll
    for (int kt = 0; kt < 4; ++kt) {
      float4 v0 = *(const float4*)(fr + kt * 32 + g * 8);
      float4 v1 = *(const float4*)(fr + kt * 32 + g * 8 + 4);
      short8 s;
      s[0] = (short)f2b(v0.x); s[1] = (short)f2b(v0.y);
      s[2] = (short)f2b(v0.z); s[3] = (short)f2b(v0.w);
      s[4] = (short)f2b(v1.x); s[5] = (short)f2b(v1.y);
      s[6] = (short)f2b(v1.z); s[7] = (short)f2b(v1.w);
      a[kt] = s;
    }
  }

  for (int t = 0; t < N_T; ++t) {
    if (t > 0) __syncthreads();                            // Bs reads of t-1 done
    {                                                      // stage B tile (linear copy)
      const uint4* src = (const uint4*)(Btg + (size_t)t * TILE_E);
      uint4* dstv = (uint4*)Bs;
#pragma unroll
      for (int i = 0; i < 9; ++i)
        dstv[i * 256 + tid] = src[i * 256 + tid];
    }
    __syncthreads();

    f32x4 acc[8];
#pragma unroll
    for (int ct = 0; ct < 8; ++ct) {
      f32x4 c = {0.f, 0.f, 0.f, 0.f};
#pragma unroll
      for (int kt = 0; kt < 4; ++kt) {
        int row = ct * 16 + l15;
        int boff = (row * 256 + kt * 64 + g * 16) ^ ((l15 & 7) << 4);
        short8 b = *(const short8*)((const char*)Bs + boff);
        c = __builtin_amdgcn_mfma_f32_16x16x32_bf16(a[kt], b, c, 0, 0, 0);
      }
      acc[ct] = c;
    }
    {                                                      // ct=8: el/er columns
      f32x4 c8 = {0.f, 0.f, 0.f, 0.f};
#pragma unroll
      for (int kt = 0; kt < 4; ++kt) {
        int row = 128 + l15;
        int boff = (row * 256 + kt * 64 + g * 16) ^ ((l15 & 7) << 4);
        short8 b = *(const short8*)((const char*)Bs + boff);
        c8 = __builtin_amdgcn_mfma_f32_16x16x32_bf16(a[kt], b, c8, 0, 0, 0);
      }
      if (l15 < 8) {
#pragma unroll
        for (int r = 0; r < 4; ++r) {
          int row = wrow0 + g * 4 + r;
          if (row < N_NODES) {
            float v = c8[r];
            if (l15 < 4) elg[((size_t)t * N_NODES + row) * 4 + l15] = v;
            else         erg[((size_t)t * N_NODES + row) * 4 + (l15 - 4)] = v;
          }
        }
      }
    }
    // direct permuted ft store: row-position p = l15*8 + ct
#pragma unroll
    for (int r = 0; r < 4; ++r) {
      int row = wrow0 + g * 4 + r;
      if (row < N_NODES) {
        uint4 o;
        o.x = pk2(acc[0][r], acc[1][r]);
        o.y = pk2(acc[2][r], acc[3][r]);
        o.z = pk2(acc[4][r], acc[5][r]);
        o.w = pk2(acc[6][r], acc[7][r]);
        *(uint4*)(ftg + ((size_t)t * N_NODES + row) * HF + l15 * 8) = o;
      }
    }
  }
}

// K2: counting sort of kept edges by (t,dst)
__global__ __launch_bounds__(256) void k_hist(const int* __restrict__ dst, int* __restrict__ cnt) {
  int idx = blockIdx.x * 256 + threadIdx.x;
  if (idx >= TE) return;
  int t = idx / N_EDGES;
  int d = dst[idx];
  bool keep = (t < 2) ? (d < N_A) : (d >= N_A);
  if (keep) atomicAdd(&cnt[t * N_NODES + d], 1);
}

__global__ __launch_bounds__(256) void k_scan1(const int* __restrict__ cnt,
    int* __restrict__ ofs, int* __restrict__ bsum) {
  __shared__ int ts[256];
  int b = blockIdx.x, t = threadIdx.x;
  int base = b * 1024 + t * 4;
  int v0 = 0, v1 = 0, v2 = 0, v3 = 0;
  if (base + 0 < TN) v0 = cnt[base + 0];
  if (base + 1 < TN) v1 = cnt[base + 1];
  if (base + 2 < TN) v2 = cnt[base + 2];
  if (base + 3 < TN) v3 = cnt[base + 3];
  int s = v0 + v1 + v2 + v3;
  ts[t] = s;
  __syncthreads();
  for (int o = 1; o < 256; o <<= 1) {
    int x = (t >= o) ? ts[t - o] : 0;
    __syncthreads();
    ts[t] += x;
    __syncthreads();
  }
  int run = ts[t] - s;
  if (base + 0 < TN) ofs[base + 0] = run; run += v0;
  if (base + 1 < TN) ofs[base + 1] = run; run += v1;
  if (base + 2 < TN) ofs[base + 2] = run; run += v2;
  if (base + 3 < TN) ofs[base + 3] = run;
  if (t == 255) bsum[b] = ts[255];
}

__global__ __launch_bounds__(512) void k_scan2(int* __restrict__ bsum) {
  __shared__ int ts[512];
  int t = threadIdx.x;
  int v = (t < NB1) ? bsum[t] : 0;
  ts[t] = v;
  __syncthreads();
  for (int o = 1; o < 512; o <<= 1) {
    int x = (t >= o) ? ts[t - o] : 0;
    __syncthreads();
    ts[t] += x;
    __syncthreads();
  }
  if (t < NB1) bsum[t] = ts[t] - v;
}

__global__ __launch_bounds__(256) void k_scan3(int* __restrict__ ofs, const int* __restrict__ bsum) {
  int b = blockIdx.x;
  int add = bsum[b];
  int base = b * 1024;
  for (int i = threadIdx.x; i < 1024; i += 256) {
    int j = base + i;
    if (j < TN) ofs[j] += add;
  }
}

// K3: scatter kept edges AND precompute softmax weights w[h]=exp(leaky(el+er)), bf16-packed
__global__ __launch_bounds__(256) void k_scatter(const int* __restrict__ src, const int* __restrict__ dst,
    const int* __restrict__ ofs, int* __restrict__ cur,
    const float* __restrict__ elg, const float* __restrict__ erg,
    int* __restrict__ bsrc, uint2* __restrict__ bw) {
  int idx = blockIdx.x * 256 + threadIdx.x;
  if (idx >= TE) return;
  int t = idx / N_EDGES;
  int d = dst[idx];
  bool keep = (t < 2) ? (d < N_A) : (d >= N_A);
  if (!keep) return;
  int s = src[idx];
  int key = t * N_NODES + d;
  int p = ofs[key] + atomicAdd(&cur[key], 1);
  bsrc[p] = s;
  float4 el4 = *(const float4*)(elg + ((size_t)t * N_NODES + s) * 4);
  float4 er4 = *(const float4*)(erg + ((size_t)t * N_NODES + d) * 4);
  float e, w0, w1, w2, w3;
  e = el4.x + er4.x; w0 = __expf(e > 0.f ? e : 0.2f * e);
  e = el4.y + er4.y; w1 = __expf(e > 0.f ? e : 0.2f * e);
  e = el4.z + er4.z; w2 = __expf(e > 0.f ? e : 0.2f * e);
  e = el4.w + er4.w; w3 = __expf(e > 0.f ? e : 0.2f * e);
  uint2 u;
  u.x = pk2(w0, w1);
  u.y = pk2(w2, w3);
  bw[p] = u;
}

// K4: gather, 4 edges/iter (16 lanes/edge, uint4 ft loads in PERMUTED layout:
// word x -> head0, y -> head1, z -> head2, w -> head3). 4 running denominators.
__global__ __launch_bounds__(256) void k_gather(const int* __restrict__ bsrc,
    const unsigned short* __restrict__ bwh,
    const int* __restrict__ ofs, const int* __restrict__ cnt,
    const uint4* __restrict__ ftu, uint4* __restrict__ aggb)
{
  int wid = blockIdx.x * 4 + (threadIdx.x >> 6);
  int lane = threadIdx.x & 63;
  int n = wid >> 1, slot = wid & 1;
  if (n >= N_NODES) return;
  int t = slot + ((n >= N_A) ? 2 : 0);
  int key = t * N_NODES + n;
  int base = ofs[key], c = cnt[key];
  int g = lane >> 4, l15 = lane & 15;
  float a0 = 0.f, a1 = 0.f, a2 = 0.f, a3 = 0.f, a4 = 0.f, a5 = 0.f, a6 = 0.f, a7 = 0.f;
  float d0 = 0.f, d1 = 0.f, d2 = 0.f, d3 = 0.f;
  int tbase = t * N_NODES;
  for (int i0 = 0; i0 < c; i0 += 4) {
    int j = i0 + g;
    float w0 = 0.f, w1 = 0.f, w2 = 0.f, w3 = 0.f; int s = 0;
    if (j < c) {
      int e = base + j; s = bsrc[e];
      uint2 wv = *(const uint2*)(bwh + (size_t)e * 4);
      w0 = blo(wv.x); w1 = bhi(wv.x); w2 = blo(wv.y); w3 = bhi(wv.y);
    }
    uint4 u = ftu[(size_t)(tbase + s) * 16 + l15];
    d0 += w0; d1 += w1; d2 += w2; d3 += w3;
    a0 += w0 * blo(u.x); a1 += w0 * bhi(u.x);
    a2 += w1 * blo(u.y); a3 += w1 * bhi(u.y);
    a4 += w2 * blo(u.z); a5 += w2 * bhi(u.z);
    a6 += w3 * blo(u.w); a7 += w3 * bhi(u.w);
  }
  a0 += __shfl_xor(a0, 16); a0 += __shfl_xor(a0, 32);
  a1 += __shfl_xor(a1, 16); a1 += __shfl_xor(a1, 32);
  a2 += __shfl_xor(a2, 16); a2 += __shfl_xor(a2, 32);
  a3 += __shfl_xor(a3, 16); a3 += __shfl_xor(a3, 32);
  a4 += __shfl_xor(a4, 16); a4 += __shfl_xor(a4, 32);
  a5 += __shfl_xor(a5, 16); a5 += __shfl_xor(a5, 32);
  a6 += __shfl_xor(a6, 16); a6 += __shfl_xor(a6, 32);
  a7 += __shfl_xor(a7, 16); a7 += __shfl_xor(a7, 32);
  d0 += __shfl_xor(d0, 16); d0 += __shfl_xor(d0, 32);
  d1 += __shfl_xor(d1, 16); d1 += __shfl_xor(d1, 32);
  d2 += __shfl_xor(d2, 16); d2 += __shfl_xor(d2, 32);
  d3 += __shfl_xor(d3, 16); d3 += __shfl_xor(d3, 32);
  if (lane < 16) {
    float i0 = (c > 0) ? 1.f / d0 : 0.f;
    float i1 = (c > 0) ? 1.f / d1 : 0.f;
    float i2 = (c > 0) ? 1.f / d2 : 0.f;
    float i3 = (c > 0) ? 1.f / d3 : 0.f;
    uint4 o;
    o.x = pk2(a0 * i0, a1 * i0);
    o.y = pk2(a2 * i1, a3 * i1);
    o.z = pk2(a4 * i2, a5 * i2);
    o.w = pk2(a6 * i3, a7 * i3);
    aggb[(size_t)n * 32 + slot * 16 + l15] = o;
  }
}

// K5: merge GEMM via MFMA. 64 nodes/block, out = agg(bf16, permuted-k) @ WmT + bm.
__global__ __launch_bounds__(256) void k_merge(const unsigned short* __restrict__ aggb,
    const unsigned short* __restrict__ WmT, const float* __restrict__ bm,
    float* __restrict__ out)
{
  __shared__ __align__(16) unsigned short Al[64 * 264];
  __shared__ __align__(16) unsigned short Bl[32 * 264];
  int n0 = blockIdx.x * 64;
  int tid = threadIdx.x;
  const uint4* asrc = (const uint4*)(aggb + (size_t)n0 * 256);
  for (int i = tid; i < 2048; i += 256) {
    int r = i >> 5, c = i & 31;
    *(uint4*)&Al[r * 264 + c * 8] = asrc[r * 32 + c];
  }
  for (int i = tid; i < 1024; i += 256) {
    int r = i >> 5, c = i & 31;
    *(uint4*)&Bl[r * 264 + c * 8] = ((const uint4*)WmT)[r * 32 + c];
  }
  __syncthreads();
  int wave = tid >> 6, lane = tid & 63;
  int l15 = lane & 15, lk = (lane >> 4) * 8;
  short8 a[8];
#pragma unroll
  for (int kt = 0; kt < 8; ++kt)
    a[kt] = *(const short8*)&Al[(wave * 16 + l15) * 264 + kt * 32 + lk];
  f32x4 acc0 = {0.f, 0.f, 0.f, 0.f}, acc1 = {0.f, 0.f, 0.f, 0.f};
#pragma unroll
  for (int kt = 0; kt < 8; ++kt) {
    short8 b0 = *(const short8*)&Bl[l15 * 264 + kt * 32 + lk];
    short8 b1 = *(const short8*)&Bl[(16 + l15) * 264 + kt * 32 + lk];
    acc0 = __builtin_amdgcn_mfma_f32_16x16x32_bf16(a[kt], b0, acc0, 0, 0, 0);
    acc1 = __builtin_amdgcn_mfma_f32_16x16x32_bf16(a[kt], b1, acc1, 0, 0, 0);
  }
  float bm0 = bm[l15], bm1 = bm[16 + l15];
#pragma unroll
  for (int r = 0; r < 4; ++r) {
    int row = n0 + wave * 16 + (lane >> 4) * 4 + r;
    if (row < N_NODES) {
      out[(size_t)row * 32 + l15] = acc0[r] + bm0;
      out[(size_t)row * 32 + 16 + l15] = acc1[r] + bm1;
    }
  }
}

extern "C" void kernel_launch(void* const* d_in, const int* in_sizes, int n_in,
                              void* d_out, int out_size, void* d_ws, size_t ws_size,
                              hipStream_t stream)
{
  const float* feat = (const float*)d_in[0];
  const int*   src  = (const int*)d_in[1];
  const int*   dst  = (const int*)d_in[2];
  const float* W    = (const float*)d_in[4];
  const float* al   = (const float*)d_in[5];
  const float* ar   = (const float*)d_in[6];
  const float* Wm   = (const float*)d_in[7];
  const float* bm   = (const float*)d_in[8];
  float* out = (float*)d_out;
  (void)in_sizes; (void)n_in; (void)out_size; (void)ws_size;

  char* w = (char*)d_ws;
  size_t o = 0;
  auto take = [&](size_t bytes) -> void* {
    void* p = w + o;
    o += (bytes + 255) & ~(size_t)255;
    return p;
  };
  unsigned short* Btg = (unsigned short*)take((size_t)N_T * TILE_E * 2);         // 147 KB
  unsigned short* WmT = (unsigned short*)take((size_t)32 * 256 * 2);             // 16 KB
  unsigned short* ftg = (unsigned short*)take((size_t)N_T * N_NODES * HF * 2);   // 102.4 MB
  float* elg   = (float*)take((size_t)N_T * N_NODES * 4 * 4);                    // 6.4 MB
  float* erg   = (float*)take((size_t)N_T * N_NODES * 4 * 4);                    // 6.4 MB
  int*   cntb  = (int*)take((size_t)TN * 4);                                     // 1.6 MB
  int*   ofs   = (int*)take((size_t)TN * 4);
  int*   cur   = (int*)take((size_t)TN * 4);
  int*   bsum  = (int*)take(4096);
  int*   bsrc  = (int*)take((size_t)TE * 4);                                     // 8 MB
  uint2* bwgt  = (uint2*)take((size_t)TE * 8);                                   // 16 MB
  unsigned short* aggb = (unsigned short*)take((size_t)(N_NODES + 64) * 256 * 2);// 51.2 MB

  hipMemsetAsync(cntb, 0, (size_t)TN * 4, stream);
  hipMemsetAsync(cur,  0, (size_t)TN * 4, stream);

  k_prepB<<<2, 256, 0, stream>>>(W, al, ar, Btg);
  k_prepWm<<<32, 256, 0, stream>>>(Wm, WmT);
  k_proj<<<1563, 256, 0, stream>>>(feat, Btg, ftg, elg, erg);
  k_hist<<<(TE + 255) / 256, 256, 0, stream>>>(dst, cntb);
  k_scan1<<<NB1, 256, 0, stream>>>(cntb, ofs, bsum);
  k_scan2<<<1, 512, 0, stream>>>(bsum);
  k_scan3<<<NB1, 256, 0, stream>>>(ofs, bsum);
  k_scatter<<<(TE + 255) / 256, 256, 0, stream>>>(src, dst, ofs, cur, elg, erg, bsrc, bwgt);
  k_gather<<<50000, 256, 0, stream>>>(bsrc, (const unsigned short*)bwgt, ofs, cntb, (const uint4*)ftg, (uint4*)aggb);
  k_merge<<<1563, 256, 0, stream>>>(aggb, WmT, bm, out);
}

// Round 5
// 244.973 us; speedup vs baseline: 1.7613x; 1.1440x over previous
//
#include <hip/hip_runtime.h>

typedef short short8 __attribute__((ext_vector_type(8)));
typedef float f32x4 __attribute__((ext_vector_type(4)));

#define N_NODES 100000
#define N_A     50000
#define N_EDGES 500000
#define N_T     4
#define D_IN    128
#define HF      128
#define BCOLS   144                  // 128 ft cols + 4 el + 4 er + 8 zero pad
#define TN      (N_T * N_NODES)
#define TE      (N_T * N_EDGES)
#define NB1     ((TN + 1023) / 1024) // 391 scan blocks
#define TILE_E  (BCOLS * D_IN)       // 18432 elems = 36864 B per (t) B-tile

__device__ __forceinline__ unsigned short f2b(float f) {
  unsigned int u = __float_as_uint(f);
  u += 0x7FFFu + ((u >> 16) & 1u);
  return (unsigned short)(u >> 16);
}
__device__ __forceinline__ unsigned int pk2(float lo, float hi) {
  return (unsigned int)f2b(lo) | ((unsigned int)f2b(hi) << 16);
}
__device__ __forceinline__ float blo(unsigned int u) { return __uint_as_float(u << 16); }
__device__ __forceinline__ float bhi(unsigned int u) { return __uint_as_float(u & 0xFFFF0000u); }

// K0a: build Bt[t][144][128] bf16, XOR-SWIZZLED: element (j,k) stored at
// linear index (j*128+k) ^ ((j&7)<<3)  [= byte addr ^ ((row&7)<<4)].
// Rows: 0..127 = W[t][:,j]; 128+h = W@attn_l[h]; 132+h = W@attn_r[h]; 136..143 = 0
__global__ __launch_bounds__(256) void k_prepB(const float* __restrict__ W,
    const float* __restrict__ al, const float* __restrict__ ar,
    unsigned short* __restrict__ Bt)
{
  int idx = blockIdx.x * 256 + threadIdx.x;
  if (idx >= N_T * D_IN) return;
  int t = idx >> 7, k = idx & 127;
  const float* Wr = W + ((size_t)t * D_IN + k) * HF;
  unsigned short* o = Bt + (size_t)t * TILE_E;
  for (int j = 0; j < HF; ++j)
    o[(j * D_IN + k) ^ ((j & 7) << 3)] = f2b(Wr[j]);
  for (int h = 0; h < 4; ++h) {
    float sl = 0.f, sr = 0.f;
    const float* alh = al + (t * 4 + h) * 32;
    const float* arh = ar + (t * 4 + h) * 32;
    for (int f = 0; f < 32; ++f) { float w = Wr[h * 32 + f]; sl += w * alh[f]; sr += w * arh[f]; }
    int jl = 128 + h, jr = 132 + h;
    o[(jl * D_IN + k) ^ ((jl & 7) << 3)] = f2b(sl);
    o[(jr * D_IN + k) ^ ((jr & 7) << 3)] = f2b(sr);
  }
  for (int j = 136; j < 144; ++j)
    o[(j * D_IN + k) ^ ((j & 7) << 3)] = 0;
}

// K0b: WmT[j][kidx] bf16 where kidx = slot*128 + p and p is the PERMUTED ft
// position: col(p) = (p&7)*16 + (p>>3).
__global__ __launch_bounds__(256) void k_prepWm(const float* __restrict__ Wm,
    unsigned short* __restrict__ WmT)
{
  int idx = blockIdx.x * 256 + threadIdx.x;
  if (idx >= 256 * 32) return;
  int kidx = idx >> 5, j = idx & 31;
  int slot = kidx >> 7, p = kidx & 127;
  int col = (p & 7) * 16 + (p >> 3);
  WmT[j * 256 + kidx] = f2b(Wm[(slot * 128 + col) * 32 + j]);
}

// K1: projection GEMM. Block = 64 rows (4 waves x 16 rows), grid 1563.
// A-frags from global feat (f32->bf16 in reg, loaded once). B staged in LDS
// per t (pre-swizzled -> linear copy), read via swizzled ds_read_b128.
// ft written DIRECTLY from accumulators in permuted layout (no transpose).
__global__ __launch_bounds__(256, 4) void k_proj(const float* __restrict__ feat,
    const unsigned short* __restrict__ Btg,
    unsigned short* __restrict__ ftg,
    float* __restrict__ elg, float* __restrict__ erg)
{
  __shared__ __align__(16) unsigned short Bs[TILE_E];      // 36.8 KB -> 4 blocks/CU
  const int tid = threadIdx.x;
  const int wave = tid >> 6, lane = tid & 63;
  const int l15 = lane & 15, g = lane >> 4;
  const int wrow0 = blockIdx.x * 64 + wave * 16;

  // A fragments: row = wrow0 + l15, k = kt*32 + g*8 + j (clamped; stores guarded)
  short8 a[4];
  {
    int row = wrow0 + l15;
    const float* fr = feat + (size_t)(row < N_NODES ? row : N_NODES - 1) * D_IN;
#pragma unroll
    for (int kt = 0; kt < 4; ++kt) {
      float4 v0 = *(const float4*)(fr + kt * 32 + g * 8);
      float4 v1 = *(const float4*)(fr + kt * 32 + g * 8 + 4);
      short8 s;
      s[0] = (short)f2b(v0.x); s[1] = (short)f2b(v0.y);
      s[2] = (short)f2b(v0.z); s[3] = (short)f2b(v0.w);
      s[4] = (short)f2b(v1.x); s[5] = (short)f2b(v1.y);
      s[6] = (short)f2b(v1.z); s[7] = (short)f2b(v1.w);
      a[kt] = s;
    }
  }

  for (int t = 0; t < N_T; ++t) {
    if (t > 0) __syncthreads();                            // Bs reads of t-1 done
    {                                                      // stage B tile (linear copy)
      const uint4* src = (const uint4*)(Btg + (size_t)t * TILE_E);
      uint4* dstv = (uint4*)Bs;
#pragma unroll
      for (int i = 0; i < 9; ++i)
        dstv[i * 256 + tid] = src[i * 256 + tid];
    }
    __syncthreads();

    f32x4 acc[8];
#pragma unroll
    for (int ct = 0; ct < 8; ++ct) {
      f32x4 c = {0.f, 0.f, 0.f, 0.f};
#pragma unroll
      for (int kt = 0; kt < 4; ++kt) {
        int row = ct * 16 + l15;
        int boff = (row * 256 + kt * 64 + g * 16) ^ ((l15 & 7) << 4);
        short8 b = *(const short8*)((const char*)Bs + boff);
        c = __builtin_amdgcn_mfma_f32_16x16x32_bf16(a[kt], b, c, 0, 0, 0);
      }
      acc[ct] = c;
    }
    {                                                      // ct=8: el/er columns
      f32x4 c8 = {0.f, 0.f, 0.f, 0.f};
#pragma unroll
      for (int kt = 0; kt < 4; ++kt) {
        int row = 128 + l15;
        int boff = (row * 256 + kt * 64 + g * 16) ^ ((l15 & 7) << 4);
        short8 b = *(const short8*)((const char*)Bs + boff);
        c8 = __builtin_amdgcn_mfma_f32_16x16x32_bf16(a[kt], b, c8, 0, 0, 0);
      }
      if (l15 < 8) {
#pragma unroll
        for (int r = 0; r < 4; ++r) {
          int row = wrow0 + g * 4 + r;
          if (row < N_NODES) {
            float v = c8[r];
            if (l15 < 4) elg[((size_t)t * N_NODES + row) * 4 + l15] = v;
            else         erg[((size_t)t * N_NODES + row) * 4 + (l15 - 4)] = v;
          }
        }
      }
    }
    // direct permuted ft store: row-position p = l15*8 + ct
#pragma unroll
    for (int r = 0; r < 4; ++r) {
      int row = wrow0 + g * 4 + r;
      if (row < N_NODES) {
        uint4 o;
        o.x = pk2(acc[0][r], acc[1][r]);
        o.y = pk2(acc[2][r], acc[3][r]);
        o.z = pk2(acc[4][r], acc[5][r]);
        o.w = pk2(acc[6][r], acc[7][r]);
        *(uint4*)(ftg + ((size_t)t * N_NODES + row) * HF + l15 * 8) = o;
      }
    }
  }
}

// K2: counting sort of kept edges by (t,dst)
__global__ __launch_bounds__(256) void k_hist(const int* __restrict__ dst, int* __restrict__ cnt) {
  int idx = blockIdx.x * 256 + threadIdx.x;
  if (idx >= TE) return;
  int t = idx / N_EDGES;
  int d = dst[idx];
  bool keep = (t < 2) ? (d < N_A) : (d >= N_A);
  if (keep) atomicAdd(&cnt[t * N_NODES + d], 1);
}

__global__ __launch_bounds__(256) void k_scan1(const int* __restrict__ cnt,
    int* __restrict__ ofs, int* __restrict__ bsum) {
  __shared__ int ts[256];
  int b = blockIdx.x, t = threadIdx.x;
  int base = b * 1024 + t * 4;
  int v0 = 0, v1 = 0, v2 = 0, v3 = 0;
  if (base + 0 < TN) v0 = cnt[base + 0];
  if (base + 1 < TN) v1 = cnt[base + 1];
  if (base + 2 < TN) v2 = cnt[base + 2];
  if (base + 3 < TN) v3 = cnt[base + 3];
  int s = v0 + v1 + v2 + v3;
  ts[t] = s;
  __syncthreads();
  for (int o = 1; o < 256; o <<= 1) {
    int x = (t >= o) ? ts[t - o] : 0;
    __syncthreads();
    ts[t] += x;
    __syncthreads();
  }
  int run = ts[t] - s;
  if (base + 0 < TN) ofs[base + 0] = run; run += v0;
  if (base + 1 < TN) ofs[base + 1] = run; run += v1;
  if (base + 2 < TN) ofs[base + 2] = run; run += v2;
  if (base + 3 < TN) ofs[base + 3] = run;
  if (t == 255) bsum[b] = ts[255];
}

__global__ __launch_bounds__(512) void k_scan2(int* __restrict__ bsum) {
  __shared__ int ts[512];
  int t = threadIdx.x;
  int v = (t < NB1) ? bsum[t] : 0;
  ts[t] = v;
  __syncthreads();
  for (int o = 1; o < 512; o <<= 1) {
    int x = (t >= o) ? ts[t - o] : 0;
    __syncthreads();
    ts[t] += x;
    __syncthreads();
  }
  if (t < NB1) bsum[t] = ts[t] - v;
}

__global__ __launch_bounds__(256) void k_scan3(int* __restrict__ ofs, const int* __restrict__ bsum) {
  int b = blockIdx.x;
  int add = bsum[b];
  int base = b * 1024;
  for (int i = threadIdx.x; i < 1024; i += 256) {
    int j = base + i;
    if (j < TN) ofs[j] += add;
  }
}

// K3: scatter kept edges as fused 16 B records: {ft_row_idx, 0, w01, w23}
// with w[h] = exp(leaky(el+er)) packed bf16.
__global__ __launch_bounds__(256) void k_scatter(const int* __restrict__ src, const int* __restrict__ dst,
    const int* __restrict__ ofs, int* __restrict__ cur,
    const float* __restrict__ elg, const float* __restrict__ erg,
    uint4* __restrict__ bkt) {
  int idx = blockIdx.x * 256 + threadIdx.x;
  if (idx >= TE) return;
  int t = idx / N_EDGES;
  int d = dst[idx];
  bool keep = (t < 2) ? (d < N_A) : (d >= N_A);
  if (!keep) return;
  int s = src[idx];
  int key = t * N_NODES + d;
  int p = ofs[key] + atomicAdd(&cur[key], 1);
  float4 el4 = *(const float4*)(elg + ((size_t)t * N_NODES + s) * 4);
  float4 er4 = *(const float4*)(erg + ((size_t)t * N_NODES + d) * 4);
  float e, w0, w1, w2, w3;
  e = el4.x + er4.x; w0 = __expf(e > 0.f ? e : 0.2f * e);
  e = el4.y + er4.y; w1 = __expf(e > 0.f ? e : 0.2f * e);
  e = el4.z + er4.z; w2 = __expf(e > 0.f ? e : 0.2f * e);
  e = el4.w + er4.w; w3 = __expf(e > 0.f ? e : 0.2f * e);
  uint4 rec;
  rec.x = (unsigned int)(t * N_NODES + s);   // ft row index
  rec.y = 0u;
  rec.z = pk2(w0, w1);
  rec.w = pk2(w2, w3);
  bkt[p] = rec;
}

// K4: gather. 4 pairs per wave, 16 lanes per pair. Each group walks its own
// edge list: one 16 B record load (broadcast) + one 256 B ft row per edge.
// 2x unrolled for MLP. No cross-lane reduction; coalesced 1 KB wave store.
__global__ __launch_bounds__(256) void k_gather(const uint4* __restrict__ bkt,
    const int* __restrict__ ofs, const int* __restrict__ cnt,
    const uint4* __restrict__ ftu, uint4* __restrict__ aggb)
{
  int wid = blockIdx.x * 4 + (threadIdx.x >> 6);
  int lane = threadIdx.x & 63;
  int g = lane >> 4, l15 = lane & 15;
  int pid = wid * 4 + g;                       // pair id = node*2 + slot
  int n = pid >> 1, slot = pid & 1;
  int t = slot + ((n >= N_A) ? 2 : 0);
  int key = t * N_NODES + n;
  int base = ofs[key], c = cnt[key];
  float a0 = 0.f, a1 = 0.f, a2 = 0.f, a3 = 0.f, a4 = 0.f, a5 = 0.f, a6 = 0.f, a7 = 0.f;
  float d0 = 0.f, d1 = 0.f, d2 = 0.f, d3 = 0.f;
  int i = 0;
  for (; i + 1 < c; i += 2) {
    uint4 r0 = bkt[base + i];
    uint4 r1 = bkt[base + i + 1];
    uint4 u0 = ftu[(size_t)r0.x * 16 + l15];
    uint4 u1 = ftu[(size_t)r1.x * 16 + l15];
    float w0, w1, w2, w3;
    w0 = blo(r0.z); w1 = bhi(r0.z); w2 = blo(r0.w); w3 = bhi(r0.w);
    d0 += w0; d1 += w1; d2 += w2; d3 += w3;
    a0 += w0 * blo(u0.x); a1 += w0 * bhi(u0.x);
    a2 += w1 * blo(u0.y); a3 += w1 * bhi(u0.y);
    a4 += w2 * blo(u0.z); a5 += w2 * bhi(u0.z);
    a6 += w3 * blo(u0.w); a7 += w3 * bhi(u0.w);
    w0 = blo(r1.z); w1 = bhi(r1.z); w2 = blo(r1.w); w3 = bhi(r1.w);
    d0 += w0; d1 += w1; d2 += w2; d3 += w3;
    a0 += w0 * blo(u1.x); a1 += w0 * bhi(u1.x);
    a2 += w1 * blo(u1.y); a3 += w1 * bhi(u1.y);
    a4 += w2 * blo(u1.z); a5 += w2 * bhi(u1.z);
    a6 += w3 * blo(u1.w); a7 += w3 * bhi(u1.w);
  }
  if (i < c) {
    uint4 r0 = bkt[base + i];
    uint4 u0 = ftu[(size_t)r0.x * 16 + l15];
    float w0 = blo(r0.z), w1 = bhi(r0.z), w2 = blo(r0.w), w3 = bhi(r0.w);
    d0 += w0; d1 += w1; d2 += w2; d3 += w3;
    a0 += w0 * blo(u0.x); a1 += w0 * bhi(u0.x);
    a2 += w1 * blo(u0.y); a3 += w1 * bhi(u0.y);
    a4 += w2 * blo(u0.z); a5 += w2 * bhi(u0.z);
    a6 += w3 * blo(u0.w); a7 += w3 * bhi(u0.w);
  }
  float i0 = (c > 0) ? 1.f / d0 : 0.f;
  float i1 = (c > 0) ? 1.f / d1 : 0.f;
  float i2 = (c > 0) ? 1.f / d2 : 0.f;
  float i3 = (c > 0) ? 1.f / d3 : 0.f;
  uint4 o;
  o.x = pk2(a0 * i0, a1 * i0);
  o.y = pk2(a2 * i1, a3 * i1);
  o.z = pk2(a4 * i2, a5 * i2);
  o.w = pk2(a6 * i3, a7 * i3);
  aggb[(size_t)n * 32 + slot * 16 + l15] = o;
}

// K5: merge GEMM via MFMA. 64 nodes/block, out = agg(bf16, permuted-k) @ WmT + bm.
__global__ __launch_bounds__(256) void k_merge(const unsigned short* __restrict__ aggb,
    const unsigned short* __restrict__ WmT, const float* __restrict__ bm,
    float* __restrict__ out)
{
  __shared__ __align__(16) unsigned short Al[64 * 264];
  __shared__ __align__(16) unsigned short Bl[32 * 264];
  int n0 = blockIdx.x * 64;
  int tid = threadIdx.x;
  const uint4* asrc = (const uint4*)(aggb + (size_t)n0 * 256);
  for (int i = tid; i < 2048; i += 256) {
    int r = i >> 5, c = i & 31;
    *(uint4*)&Al[r * 264 + c * 8] = asrc[r * 32 + c];
  }
  for (int i = tid; i < 1024; i += 256) {
    int r = i >> 5, c = i & 31;
    *(uint4*)&Bl[r * 264 + c * 8] = ((const uint4*)WmT)[r * 32 + c];
  }
  __syncthreads();
  int wave = tid >> 6, lane = tid & 63;
  int l15 = lane & 15, lk = (lane >> 4) * 8;
  short8 a[8];
#pragma unroll
  for (int kt = 0; kt < 8; ++kt)
    a[kt] = *(const short8*)&Al[(wave * 16 + l15) * 264 + kt * 32 + lk];
  f32x4 acc0 = {0.f, 0.f, 0.f, 0.f}, acc1 = {0.f, 0.f, 0.f, 0.f};
#pragma unroll
  for (int kt = 0; kt < 8; ++kt) {
    short8 b0 = *(const short8*)&Bl[l15 * 264 + kt * 32 + lk];
    short8 b1 = *(const short8*)&Bl[(16 + l15) * 264 + kt * 32 + lk];
    acc0 = __builtin_amdgcn_mfma_f32_16x16x32_bf16(a[kt], b0, acc0, 0, 0, 0);
    acc1 = __builtin_amdgcn_mfma_f32_16x16x32_bf16(a[kt], b1, acc1, 0, 0, 0);
  }
  float bm0 = bm[l15], bm1 = bm[16 + l15];
#pragma unroll
  for (int r = 0; r < 4; ++r) {
    int row = n0 + wave * 16 + (lane >> 4) * 4 + r;
    if (row < N_NODES) {
      out[(size_t)row * 32 + l15] = acc0[r] + bm0;
      out[(size_t)row * 32 + 16 + l15] = acc1[r] + bm1;
    }
  }
}

extern "C" void kernel_launch(void* const* d_in, const int* in_sizes, int n_in,
                              void* d_out, int out_size, void* d_ws, size_t ws_size,
                              hipStream_t stream)
{
  const float* feat = (const float*)d_in[0];
  const int*   src  = (const int*)d_in[1];
  const int*   dst  = (const int*)d_in[2];
  const float* W    = (const float*)d_in[4];
  const float* al   = (const float*)d_in[5];
  const float* ar   = (const float*)d_in[6];
  const float* Wm   = (const float*)d_in[7];
  const float* bm   = (const float*)d_in[8];
  float* out = (float*)d_out;
  (void)in_sizes; (void)n_in; (void)out_size; (void)ws_size;

  char* w = (char*)d_ws;
  size_t o = 0;
  auto take = [&](size_t bytes) -> void* {
    void* p = w + o;
    o += (bytes + 255) & ~(size_t)255;
    return p;
  };
  unsigned short* Btg = (unsigned short*)take((size_t)N_T * TILE_E * 2);         // 147 KB
  unsigned short* WmT = (unsigned short*)take((size_t)32 * 256 * 2);             // 16 KB
  unsigned short* ftg = (unsigned short*)take((size_t)N_T * N_NODES * HF * 2);   // 102.4 MB
  float* elg   = (float*)take((size_t)N_T * N_NODES * 4 * 4);                    // 6.4 MB
  float* erg   = (float*)take((size_t)N_T * N_NODES * 4 * 4);                    // 6.4 MB
  int*   cntb  = (int*)take((size_t)TN * 4);                                     // 1.6 MB
  int*   ofs   = (int*)take((size_t)TN * 4);
  int*   cur   = (int*)take((size_t)TN * 4);
  int*   bsum  = (int*)take(4096);
  uint4* bkt   = (uint4*)take((size_t)TE * 16);                                  // 32 MB
  unsigned short* aggb = (unsigned short*)take((size_t)(N_NODES + 64) * 256 * 2);// 51.2 MB

  hipMemsetAsync(cntb, 0, (size_t)TN * 4, stream);
  hipMemsetAsync(cur,  0, (size_t)TN * 4, stream);

  k_prepB<<<2, 256, 0, stream>>>(W, al, ar, Btg);
  k_prepWm<<<32, 256, 0, stream>>>(Wm, WmT);
  k_proj<<<1563, 256, 0, stream>>>(feat, Btg, ftg, elg, erg);
  k_hist<<<(TE + 255) / 256, 256, 0, stream>>>(dst, cntb);
  k_scan1<<<NB1, 256, 0, stream>>>(cntb, ofs, bsum);
  k_scan2<<<1, 512, 0, stream>>>(bsum);
  k_scan3<<<NB1, 256, 0, stream>>>(ofs, bsum);
  k_scatter<<<(TE + 255) / 256, 256, 0, stream>>>(src, dst, ofs, cur, elg, erg, bkt);
  k_gather<<<12500, 256, 0, stream>>>(bkt, ofs, cntb, (const uint4*)ftg, (uint4*)aggb);
  k_merge<<<1563, 256, 0, stream>>>(aggb, WmT, bm, out);
}

// Round 6
// 201.978 us; speedup vs baseline: 2.1362x; 1.2129x over previous
//
#include <hip/hip_runtime.h>

typedef short short8 __attribute__((ext_vector_type(8)));
typedef float f32x4 __attribute__((ext_vector_type(4)));

#define N_NODES 100000
#define N_A     50000
#define N_EDGES 500000
#define N_T     4
#define D_IN    128
#define HF      128
#define BCOLS   144                  // 128 ft cols + 4 el + 4 er + 8 zero pad
#define TN      (N_T * N_NODES)
#define TE      (N_T * N_EDGES)
#define NB1     ((TN + 1023) / 1024) // 391 scan blocks
#define TILE_E  (BCOLS * D_IN)       // 18432 elems = 36864 B per (t) B-tile

__device__ __forceinline__ unsigned short f2b(float f) {
  unsigned int u = __float_as_uint(f);
  u += 0x7FFFu + ((u >> 16) & 1u);
  return (unsigned short)(u >> 16);
}
__device__ __forceinline__ unsigned int pk2(float lo, float hi) {
  return (unsigned int)f2b(lo) | ((unsigned int)f2b(hi) << 16);
}
__device__ __forceinline__ float blo(unsigned int u) { return __uint_as_float(u << 16); }
__device__ __forceinline__ float bhi(unsigned int u) { return __uint_as_float(u & 0xFFFF0000u); }
__device__ __forceinline__ float lrelu_exp(float e) {
  return __expf(e > 0.f ? e : 0.2f * e);
}

// K0a: build Bt[t][144][128] bf16, XOR-SWIZZLED: element (j,k) stored at
// linear index (j*128+k) ^ ((j&7)<<3)  [= byte addr ^ ((row&7)<<4)].
// Rows: 0..127 = W[t][:,j]; 128+h = W@attn_l[h]; 132+h = W@attn_r[h]; 136..143 = 0
__global__ __launch_bounds__(256) void k_prepB(const float* __restrict__ W,
    const float* __restrict__ al, const float* __restrict__ ar,
    unsigned short* __restrict__ Bt)
{
  int idx = blockIdx.x * 256 + threadIdx.x;
  if (idx >= N_T * D_IN) return;
  int t = idx >> 7, k = idx & 127;
  const float* Wr = W + ((size_t)t * D_IN + k) * HF;
  unsigned short* o = Bt + (size_t)t * TILE_E;
  for (int j = 0; j < HF; ++j)
    o[(j * D_IN + k) ^ ((j & 7) << 3)] = f2b(Wr[j]);
  for (int h = 0; h < 4; ++h) {
    float sl = 0.f, sr = 0.f;
    const float* alh = al + (t * 4 + h) * 32;
    const float* arh = ar + (t * 4 + h) * 32;
    for (int f = 0; f < 32; ++f) { float w = Wr[h * 32 + f]; sl += w * alh[f]; sr += w * arh[f]; }
    int jl = 128 + h, jr = 132 + h;
    o[(jl * D_IN + k) ^ ((jl & 7) << 3)] = f2b(sl);
    o[(jr * D_IN + k) ^ ((jr & 7) << 3)] = f2b(sr);
  }
  for (int j = 136; j < 144; ++j)
    o[(j * D_IN + k) ^ ((j & 7) << 3)] = 0;
}

// K0b: WmT[j][kidx] bf16 where kidx = slot*128 + p and p is the PERMUTED ft
// position: col(p) = (p&7)*16 + (p>>3).
__global__ __launch_bounds__(256) void k_prepWm(const float* __restrict__ Wm,
    unsigned short* __restrict__ WmT)
{
  int idx = blockIdx.x * 256 + threadIdx.x;
  if (idx >= 256 * 32) return;
  int kidx = idx >> 5, j = idx & 31;
  int slot = kidx >> 7, p = kidx & 127;
  int col = (p & 7) * 16 + (p >> 3);
  WmT[j * 256 + kidx] = f2b(Wm[(slot * 128 + col) * 32 + j]);
}

// K1: projection GEMM. Block = 64 rows (4 waves x 16 rows), grid 1563.
// A-frags from global feat (f32->bf16 in reg, loaded once). B staged in LDS
// per t (pre-swizzled -> linear copy), read via swizzled ds_read_b128.
// ft written DIRECTLY from accumulators in permuted layout (no transpose).
__global__ __launch_bounds__(256, 4) void k_proj(const float* __restrict__ feat,
    const unsigned short* __restrict__ Btg,
    unsigned short* __restrict__ ftg,
    float* __restrict__ elg, float* __restrict__ erg)
{
  __shared__ __align__(16) unsigned short Bs[TILE_E];      // 36.8 KB -> 4 blocks/CU
  const int tid = threadIdx.x;
  const int wave = tid >> 6, lane = tid & 63;
  const int l15 = lane & 15, g = lane >> 4;
  const int wrow0 = blockIdx.x * 64 + wave * 16;

  // A fragments: row = wrow0 + l15, k = kt*32 + g*8 + j (clamped; stores guarded)
  short8 a[4];
  {
    int row = wrow0 + l15;
    const float* fr = feat + (size_t)(row < N_NODES ? row : N_NODES - 1) * D_IN;
#pragma unroll
    for (int kt = 0; kt < 4; ++kt) {
      float4 v0 = *(const float4*)(fr + kt * 32 + g * 8);
      float4 v1 = *(const float4*)(fr + kt * 32 + g * 8 + 4);
      short8 s;
      s[0] = (short)f2b(v0.x); s[1] = (short)f2b(v0.y);
      s[2] = (short)f2b(v0.z); s[3] = (short)f2b(v0.w);
      s[4] = (short)f2b(v1.x); s[5] = (short)f2b(v1.y);
      s[6] = (short)f2b(v1.z); s[7] = (short)f2b(v1.w);
      a[kt] = s;
    }
  }

  for (int t = 0; t < N_T; ++t) {
    if (t > 0) __syncthreads();                            // Bs reads of t-1 done
    {                                                      // stage B tile (linear copy)
      const uint4* src = (const uint4*)(Btg + (size_t)t * TILE_E);
      uint4* dstv = (uint4*)Bs;
#pragma unroll
      for (int i = 0; i < 9; ++i)
        dstv[i * 256 + tid] = src[i * 256 + tid];
    }
    __syncthreads();

    f32x4 acc[8];
#pragma unroll
    for (int ct = 0; ct < 8; ++ct) {
      f32x4 c = {0.f, 0.f, 0.f, 0.f};
#pragma unroll
      for (int kt = 0; kt < 4; ++kt) {
        int row = ct * 16 + l15;
        int boff = (row * 256 + kt * 64 + g * 16) ^ ((l15 & 7) << 4);
        short8 b = *(const short8*)((const char*)Bs + boff);
        c = __builtin_amdgcn_mfma_f32_16x16x32_bf16(a[kt], b, c, 0, 0, 0);
      }
      acc[ct] = c;
    }
    {                                                      // ct=8: el/er columns
      f32x4 c8 = {0.f, 0.f, 0.f, 0.f};
#pragma unroll
      for (int kt = 0; kt < 4; ++kt) {
        int row = 128 + l15;
        int boff = (row * 256 + kt * 64 + g * 16) ^ ((l15 & 7) << 4);
        short8 b = *(const short8*)((const char*)Bs + boff);
        c8 = __builtin_amdgcn_mfma_f32_16x16x32_bf16(a[kt], b, c8, 0, 0, 0);
      }
      if (l15 < 8) {
#pragma unroll
        for (int r = 0; r < 4; ++r) {
          int row = wrow0 + g * 4 + r;
          if (row < N_NODES) {
            float v = c8[r];
            if (l15 < 4) elg[((size_t)t * N_NODES + row) * 4 + l15] = v;
            else         erg[((size_t)t * N_NODES + row) * 4 + (l15 - 4)] = v;
          }
        }
      }
    }
    // direct permuted ft store: row-position p = l15*8 + ct
#pragma unroll
    for (int r = 0; r < 4; ++r) {
      int row = wrow0 + g * 4 + r;
      if (row < N_NODES) {
        uint4 o;
        o.x = pk2(acc[0][r], acc[1][r]);
        o.y = pk2(acc[2][r], acc[3][r]);
        o.z = pk2(acc[4][r], acc[5][r]);
        o.w = pk2(acc[6][r], acc[7][r]);
        *(uint4*)(ftg + ((size_t)t * N_NODES + row) * HF + l15 * 8) = o;
      }
    }
  }
}

// K2: histogram of kept edges by (t,dst) + per-edge within-bucket rank
__global__ __launch_bounds__(256) void k_hist(const int* __restrict__ dst,
    int* __restrict__ cnt, int* __restrict__ rank) {
  int idx = blockIdx.x * 256 + threadIdx.x;
  if (idx >= TE) return;
  int t = idx / N_EDGES;
  int d = dst[idx];
  bool keep = (t < 2) ? (d < N_A) : (d >= N_A);
  if (keep) rank[idx] = atomicAdd(&cnt[t * N_NODES + d], 1);
}

__global__ __launch_bounds__(256) void k_scan1(const int* __restrict__ cnt,
    int* __restrict__ ofs, int* __restrict__ bsum) {
  __shared__ int ts[256];
  int b = blockIdx.x, t = threadIdx.x;
  int base = b * 1024 + t * 4;
  int v0 = 0, v1 = 0, v2 = 0, v3 = 0;
  if (base + 0 < TN) v0 = cnt[base + 0];
  if (base + 1 < TN) v1 = cnt[base + 1];
  if (base + 2 < TN) v2 = cnt[base + 2];
  if (base + 3 < TN) v3 = cnt[base + 3];
  int s = v0 + v1 + v2 + v3;
  ts[t] = s;
  __syncthreads();
  for (int o = 1; o < 256; o <<= 1) {
    int x = (t >= o) ? ts[t - o] : 0;
    __syncthreads();
    ts[t] += x;
    __syncthreads();
  }
  int run = ts[t] - s;
  if (base + 0 < TN) ofs[base + 0] = run; run += v0;
  if (base + 1 < TN) ofs[base + 1] = run; run += v1;
  if (base + 2 < TN) ofs[base + 2] = run; run += v2;
  if (base + 3 < TN) ofs[base + 3] = run;
  if (t == 255) bsum[b] = ts[255];
}

__global__ __launch_bounds__(512) void k_scan2(int* __restrict__ bsum) {
  __shared__ int ts[512];
  int t = threadIdx.x;
  int v = (t < NB1) ? bsum[t] : 0;
  ts[t] = v;
  __syncthreads();
  for (int o = 1; o < 512; o <<= 1) {
    int x = (t >= o) ? ts[t - o] : 0;
    __syncthreads();
    ts[t] += x;
    __syncthreads();
  }
  if (t < NB1) bsum[t] = ts[t] - v;
}

// K3: slim scatter: 4 B record = src ft-row index; position from ofs+bsum+rank.
__global__ __launch_bounds__(256) void k_scatter(const int* __restrict__ src, const int* __restrict__ dst,
    const int* __restrict__ ofs, const int* __restrict__ bsum, const int* __restrict__ rank,
    int* __restrict__ bkt) {
  int idx = blockIdx.x * 256 + threadIdx.x;
  if (idx >= TE) return;
  int t = idx / N_EDGES;
  int d = dst[idx];
  bool keep = (t < 2) ? (d < N_A) : (d >= N_A);
  if (!keep) return;
  int key = t * N_NODES + d;
  int p = ofs[key] + bsum[key >> 10] + rank[idx];
  bkt[p] = t * N_NODES + src[idx];
}

// K4: gather. 4 pairs per wave, 16 lanes per pair. Per edge: 4 B record
// (broadcast) + 16 B el (broadcast) + 256 B ft row; weights computed on the
// fly: w[h] = exp(leaky(el[s][h] + er[d][h])). 2x unrolled for MLP.
__global__ __launch_bounds__(256) void k_gather(const int* __restrict__ bkt,
    const int* __restrict__ ofs, const int* __restrict__ cnt, const int* __restrict__ bsum,
    const float* __restrict__ elg, const float* __restrict__ erg,
    const uint4* __restrict__ ftu, uint4* __restrict__ aggb)
{
  int wid = blockIdx.x * 4 + (threadIdx.x >> 6);
  int lane = threadIdx.x & 63;
  int g = lane >> 4, l15 = lane & 15;
  int pid = wid * 4 + g;                       // pair id = node*2 + slot
  int n = pid >> 1, slot = pid & 1;
  int t = slot + ((n >= N_A) ? 2 : 0);
  int key = t * N_NODES + n;
  int base = ofs[key] + bsum[key >> 10];
  int c = cnt[key];
  float4 er4 = *(const float4*)(erg + (size_t)key * 4);
  float a0 = 0.f, a1 = 0.f, a2 = 0.f, a3 = 0.f, a4 = 0.f, a5 = 0.f, a6 = 0.f, a7 = 0.f;
  float d0 = 0.f, d1 = 0.f, d2 = 0.f, d3 = 0.f;
  int i = 0;
  for (; i + 1 < c; i += 2) {
    int s0 = bkt[base + i];
    int s1 = bkt[base + i + 1];
    float4 el0 = *(const float4*)(elg + (size_t)s0 * 4);
    float4 el1 = *(const float4*)(elg + (size_t)s1 * 4);
    uint4 u0 = ftu[(size_t)s0 * 16 + l15];
    uint4 u1 = ftu[(size_t)s1 * 16 + l15];
    float w0 = lrelu_exp(el0.x + er4.x);
    float w1 = lrelu_exp(el0.y + er4.y);
    float w2 = lrelu_exp(el0.z + er4.z);
    float w3 = lrelu_exp(el0.w + er4.w);
    d0 += w0; d1 += w1; d2 += w2; d3 += w3;
    a0 += w0 * blo(u0.x); a1 += w0 * bhi(u0.x);
    a2 += w1 * blo(u0.y); a3 += w1 * bhi(u0.y);
    a4 += w2 * blo(u0.z); a5 += w2 * bhi(u0.z);
    a6 += w3 * blo(u0.w); a7 += w3 * bhi(u0.w);
    w0 = lrelu_exp(el1.x + er4.x);
    w1 = lrelu_exp(el1.y + er4.y);
    w2 = lrelu_exp(el1.z + er4.z);
    w3 = lrelu_exp(el1.w + er4.w);
    d0 += w0; d1 += w1; d2 += w2; d3 += w3;
    a0 += w0 * blo(u1.x); a1 += w0 * bhi(u1.x);
    a2 += w1 * blo(u1.y); a3 += w1 * bhi(u1.y);
    a4 += w2 * blo(u1.z); a5 += w2 * bhi(u1.z);
    a6 += w3 * blo(u1.w); a7 += w3 * bhi(u1.w);
  }
  if (i < c) {
    int s0 = bkt[base + i];
    float4 el0 = *(const float4*)(elg + (size_t)s0 * 4);
    uint4 u0 = ftu[(size_t)s0 * 16 + l15];
    float w0 = lrelu_exp(el0.x + er4.x);
    float w1 = lrelu_exp(el0.y + er4.y);
    float w2 = lrelu_exp(el0.z + er4.z);
    float w3 = lrelu_exp(el0.w + er4.w);
    d0 += w0; d1 += w1; d2 += w2; d3 += w3;
    a0 += w0 * blo(u0.x); a1 += w0 * bhi(u0.x);
    a2 += w1 * blo(u0.y); a3 += w1 * bhi(u0.y);
    a4 += w2 * blo(u0.z); a5 += w2 * bhi(u0.z);
    a6 += w3 * blo(u0.w); a7 += w3 * bhi(u0.w);
  }
  float i0 = (c > 0) ? 1.f / d0 : 0.f;
  float i1 = (c > 0) ? 1.f / d1 : 0.f;
  float i2 = (c > 0) ? 1.f / d2 : 0.f;
  float i3 = (c > 0) ? 1.f / d3 : 0.f;
  uint4 o;
  o.x = pk2(a0 * i0, a1 * i0);
  o.y = pk2(a2 * i1, a3 * i1);
  o.z = pk2(a4 * i2, a5 * i2);
  o.w = pk2(a6 * i3, a7 * i3);
  aggb[(size_t)n * 32 + slot * 16 + l15] = o;
}

// K5: merge GEMM via MFMA. 64 nodes/block, out = agg(bf16, permuted-k) @ WmT + bm.
__global__ __launch_bounds__(256) void k_merge(const unsigned short* __restrict__ aggb,
    const unsigned short* __restrict__ WmT, const float* __restrict__ bm,
    float* __restrict__ out)
{
  __shared__ __align__(16) unsigned short Al[64 * 264];
  __shared__ __align__(16) unsigned short Bl[32 * 264];
  int n0 = blockIdx.x * 64;
  int tid = threadIdx.x;
  const uint4* asrc = (const uint4*)(aggb + (size_t)n0 * 256);
  for (int i = tid; i < 2048; i += 256) {
    int r = i >> 5, c = i & 31;
    *(uint4*)&Al[r * 264 + c * 8] = asrc[r * 32 + c];
  }
  for (int i = tid; i < 1024; i += 256) {
    int r = i >> 5, c = i & 31;
    *(uint4*)&Bl[r * 264 + c * 8] = ((const uint4*)WmT)[r * 32 + c];
  }
  __syncthreads();
  int wave = tid >> 6, lane = tid & 63;
  int l15 = lane & 15, lk = (lane >> 4) * 8;
  short8 a[8];
#pragma unroll
  for (int kt = 0; kt < 8; ++kt)
    a[kt] = *(const short8*)&Al[(wave * 16 + l15) * 264 + kt * 32 + lk];
  f32x4 acc0 = {0.f, 0.f, 0.f, 0.f}, acc1 = {0.f, 0.f, 0.f, 0.f};
#pragma unroll
  for (int kt = 0; kt < 8; ++kt) {
    short8 b0 = *(const short8*)&Bl[l15 * 264 + kt * 32 + lk];
    short8 b1 = *(const short8*)&Bl[(16 + l15) * 264 + kt * 32 + lk];
    acc0 = __builtin_amdgcn_mfma_f32_16x16x32_bf16(a[kt], b0, acc0, 0, 0, 0);
    acc1 = __builtin_amdgcn_mfma_f32_16x16x32_bf16(a[kt], b1, acc1, 0, 0, 0);
  }
  float bm0 = bm[l15], bm1 = bm[16 + l15];
#pragma unroll
  for (int r = 0; r < 4; ++r) {
    int row = n0 + wave * 16 + (lane >> 4) * 4 + r;
    if (row < N_NODES) {
      out[(size_t)row * 32 + l15] = acc0[r] + bm0;
      out[(size_t)row * 32 + 16 + l15] = acc1[r] + bm1;
    }
  }
}

extern "C" void kernel_launch(void* const* d_in, const int* in_sizes, int n_in,
                              void* d_out, int out_size, void* d_ws, size_t ws_size,
                              hipStream_t stream)
{
  const float* feat = (const float*)d_in[0];
  const int*   src  = (const int*)d_in[1];
  const int*   dst  = (const int*)d_in[2];
  const float* W    = (const float*)d_in[4];
  const float* al   = (const float*)d_in[5];
  const float* ar   = (const float*)d_in[6];
  const float* Wm   = (const float*)d_in[7];
  const float* bm   = (const float*)d_in[8];
  float* out = (float*)d_out;
  (void)in_sizes; (void)n_in; (void)out_size; (void)ws_size;

  char* w = (char*)d_ws;
  size_t o = 0;
  auto take = [&](size_t bytes) -> void* {
    void* p = w + o;
    o += (bytes + 255) & ~(size_t)255;
    return p;
  };
  unsigned short* Btg = (unsigned short*)take((size_t)N_T * TILE_E * 2);         // 147 KB
  unsigned short* WmT = (unsigned short*)take((size_t)32 * 256 * 2);             // 16 KB
  unsigned short* ftg = (unsigned short*)take((size_t)N_T * N_NODES * HF * 2);   // 102.4 MB
  float* elg   = (float*)take((size_t)N_T * N_NODES * 4 * 4);                    // 6.4 MB
  float* erg   = (float*)take((size_t)N_T * N_NODES * 4 * 4);                    // 6.4 MB
  int*   cntb  = (int*)take((size_t)TN * 4);                                     // 1.6 MB
  int*   ofs   = (int*)take((size_t)TN * 4);
  int*   bsum  = (int*)take(4096);
  int*   rank  = (int*)take((size_t)TE * 4);                                     // 8 MB
  int*   bkt   = (int*)take((size_t)TE * 4);                                     // 8 MB
  unsigned short* aggb = (unsigned short*)take((size_t)(N_NODES + 64) * 256 * 2);// 51.2 MB

  hipMemsetAsync(cntb, 0, (size_t)TN * 4, stream);

  k_prepB<<<2, 256, 0, stream>>>(W, al, ar, Btg);
  k_prepWm<<<32, 256, 0, stream>>>(Wm, WmT);
  k_proj<<<1563, 256, 0, stream>>>(feat, Btg, ftg, elg, erg);
  k_hist<<<(TE + 255) / 256, 256, 0, stream>>>(dst, cntb, rank);
  k_scan1<<<NB1, 256, 0, stream>>>(cntb, ofs, bsum);
  k_scan2<<<1, 512, 0, stream>>>(bsum);
  k_scatter<<<(TE + 255) / 256, 256, 0, stream>>>(src, dst, ofs, bsum, rank, bkt);
  k_gather<<<12500, 256, 0, stream>>>(bkt, ofs, cntb, bsum, elg, erg, (const uint4*)ftg, (uint4*)aggb);
  k_merge<<<1563, 256, 0, stream>>>(aggb, WmT, bm, out);
}